// Round 14
// baseline (784.356 us; speedup 1.0000x reference)
//
#include <hip/hip_runtime.h>

typedef unsigned short u16;
typedef unsigned int   u32;
typedef float f32x4 __attribute__((ext_vector_type(4)));
typedef short bf16x8 __attribute__((ext_vector_type(8)));

#define DEV static __device__ __forceinline__

DEV u16 f2b(float f){
  u32 u = __builtin_bit_cast(u32, f);
  return (u16)((u + 0x7fffu + ((u >> 16) & 1u)) >> 16);
}
DEV float b2f(u16 h){ u32 u = ((u32)h) << 16; return __builtin_bit_cast(float, u); }
DEV u32 pack2(float a, float b){ return (u32)f2b(a) | ((u32)f2b(b) << 16); }
DEV uint4 pack8(const float* f){
  uint4 r; r.x = pack2(f[0],f[1]); r.y = pack2(f[2],f[3]);
  r.z = pack2(f[4],f[5]); r.w = pack2(f[6],f[7]); return r;
}
DEV void unpack8(uint4 u, float* f){
  f[0]=b2f((u16)(u.x&0xffffu)); f[1]=b2f((u16)(u.x>>16));
  f[2]=b2f((u16)(u.y&0xffffu)); f[3]=b2f((u16)(u.y>>16));
  f[4]=b2f((u16)(u.z&0xffffu)); f[5]=b2f((u16)(u.z>>16));
  f[6]=b2f((u16)(u.w&0xffffu)); f[7]=b2f((u16)(u.w>>16));
}
// gelu-tanh via sigmoid identity: 0.5x(1+tanh(z)) = x*sigma(2z); hardware v_exp
DEV float gelu_t(float x){
  const float z2 = 1.5957691216057308f*(x + 0.044715f*x*x*x);
  return x / (1.f + __expf(-z2));
}
// async global->LDS, 16B per lane; LDS dest = wave-uniform base + lane*16
DEV void g2l16(const u16* g, u16* l){
  __builtin_amdgcn_global_load_lds(
    (const __attribute__((address_space(1))) u32*)g,
    (__attribute__((address_space(3))) u32*)l, 16, 0, 0);
}

// ---------------- LayerNorm: fp32 [rows][1024] -> bf16 ----------------
__global__ __launch_bounds__(256)
void ln_k(const float* __restrict__ x, const float* __restrict__ gamma,
          const float* __restrict__ beta, u16* __restrict__ out)
{
  const int row = blockIdx.x;
  const int t = threadIdx.x;
  const float4 v = ((const float4*)(x + (size_t)row*1024))[t];
  float s  = v.x+v.y+v.z+v.w;
  float ss = v.x*v.x+v.y*v.y+v.z*v.z+v.w*v.w;
  #pragma unroll
  for (int o=32;o;o>>=1){ s += __shfl_xor(s,o); ss += __shfl_xor(ss,o); }
  __shared__ float rs[4], rq[4];
  if ((t&63)==0){ rs[t>>6]=s; rq[t>>6]=ss; }
  __syncthreads();
  s  = rs[0]+rs[1]+rs[2]+rs[3];
  ss = rq[0]+rq[1]+rq[2]+rq[3];
  const float mean = s*(1.f/1024.f);
  const float var  = ss*(1.f/1024.f) - mean*mean;
  const float inv  = rsqrtf(var + 1e-5f);
  const float4 g4 = ((const float4*)gamma)[t];
  const float4 b4 = ((const float4*)beta)[t];
  float o[4];
  o[0]=(v.x-mean)*inv*g4.x+b4.x; o[1]=(v.y-mean)*inv*g4.y+b4.y;
  o[2]=(v.z-mean)*inv*g4.z+b4.z; o[3]=(v.w-mean)*inv*g4.w+b4.w;
  uint2 w; w.x = pack2(o[0],o[1]); w.y = pack2(o[2],o[3]);
  *(uint2*)(out + (size_t)row*1024 + t*4) = w;
}

// ------------- weight conversion: W [K][N] fp32 -> WT [N][K] bf16 -------------
__global__ __launch_bounds__(256)
void wconv_k(const float* __restrict__ W, u16* __restrict__ WT, int K, int N)
{
  __shared__ float tile[32][33];
  const int k0 = blockIdx.y<<5, n0 = blockIdx.x<<5;
  const int tx = threadIdx.x & 31, ty = threadIdx.x >> 5;   // 32 x 8
  #pragma unroll
  for (int r=0;r<32;r+=8)
    tile[ty+r][tx] = W[(size_t)(k0+ty+r)*N + n0+tx];
  __syncthreads();
  #pragma unroll
  for (int r=0;r<32;r+=8)
    WT[(size_t)(n0+ty+r)*K + k0+tx] = f2b(tile[tx][ty+r]);
}

// ---- bf16 MFMA GEMM, 256x256 tile, BK=32, dbuf + early-issue + XOR swizzle ----
// 8 waves as 2(M) x 4(N); per-wave output 128x64 (8x4 16x16 frags).
#define EPI_QKV  0
#define EPI_WO   1
#define EPI_GELU 2
#define EPI_FF2  3

template<int EPI>
__global__ __launch_bounds__(512)
void gemm3_k(const u16* __restrict__ A, const u16* __restrict__ BT,
             int K, int lda, int ldb, int N,
             u16* __restrict__ obf, float* __restrict__ of32,
             const float* __restrict__ res, const float* __restrict__ bias)
{
  __shared__ __align__(16) u16 SA[2*8192];    // [buf][256 rows][32 k]
  __shared__ __align__(16) u16 SB[2*8192];
  const int t = threadIdx.x, wid = t>>6, lane = t&63;
  const int c = lane&15, g = lane>>4;
  const int wm = wid>>2, wn = wid&3;
  const int nwg = gridDim.x*gridDim.y;
  const int lb = blockIdx.y*gridDim.x + blockIdx.x;
  const int nl = (lb&7)*(nwg>>3) + (lb>>3);
  const int bx = nl % gridDim.x, by = nl / gridDim.x;
  const int m0 = by<<8, n0 = bx<<8;
  // staging: wave-load l (l=0,1) covers rows wid*32 + l*16 + (lane>>2), chunk lane&3
  const int srow = lane>>2;
  const int schunk = ((lane&3) ^ (srow&3))<<3;        // inverse-swizzled source
  const u16* aSrc0 = A  + (size_t)(m0 + (wid<<5) + srow)*lda + schunk;
  const u16* bSrc0 = BT + (size_t)(n0 + (wid<<5) + srow)*ldb + schunk;
  const u16* aSrc1 = aSrc0 + (size_t)16*lda;
  const u16* bSrc1 = bSrc0 + (size_t)16*ldb;
  const int kx = (g<<3) ^ ((c&3)<<3);                 // swizzled frag read

  f32x4 acc[8][4];
  #pragma unroll
  for (int i=0;i<8;i++)
    #pragma unroll
    for (int j=0;j<4;j++) acc[i][j] = (f32x4){0.f,0.f,0.f,0.f};

  g2l16(aSrc0, &SA[(wid<<1)<<9]);
  g2l16(aSrc1, &SA[((wid<<1)|1)<<9]);
  g2l16(bSrc0, &SB[(wid<<1)<<9]);
  g2l16(bSrc1, &SB[((wid<<1)|1)<<9]);
  __syncthreads();

  const int nt = K >> 5;
  for (int tt = 0; tt < nt; ++tt){
    const int cur = tt & 1;
    if (tt + 1 < nt){
      const int ko = (tt+1) << 5;
      const int db = (cur^1)<<13;
      g2l16(aSrc0 + ko, &SA[db + ((wid<<1)<<9)]);
      g2l16(aSrc1 + ko, &SA[db + (((wid<<1)|1)<<9)]);
      g2l16(bSrc0 + ko, &SB[db + ((wid<<1)<<9)]);
      g2l16(bSrc1 + ko, &SB[db + (((wid<<1)|1)<<9)]);
    }
    bf16x8 af[8], bf[4];
    #pragma unroll
    for (int i=0;i<8;i++)
      af[i] = *(const bf16x8*)&SA[(cur<<13) + ((wm<<7)+(i<<4)+c)*32 + kx];
    #pragma unroll
    for (int j=0;j<4;j++)
      bf[j] = *(const bf16x8*)&SB[(cur<<13) + ((wn<<6)+(j<<4)+c)*32 + kx];
    #pragma unroll
    for (int i=0;i<8;i++)
      #pragma unroll
      for (int j=0;j<4;j++)
        acc[i][j] = __builtin_amdgcn_mfma_f32_16x16x32_bf16(af[i], bf[j], acc[i][j], 0,0,0);
    __syncthreads();
  }

  #pragma unroll
  for (int i=0;i<8;i++){
    const int gr0 = m0 + (wm<<7) + (i<<4) + (g<<2);
    #pragma unroll
    for (int j=0;j<4;j++){
      const int gc = n0 + (wn<<6) + (j<<4) + c;
      #pragma unroll
      for (int r=0;r<4;r++){
        const int gr = gr0 + r;
        const float vv = acc[i][j][r];
        if (EPI==EPI_QKV){
          obf[((size_t)(gc>>10)<<24) + (size_t)gr*1024 + (gc&1023)] = f2b(vv);
        } else if (EPI==EPI_WO){
          const size_t idx = (size_t)gr*N + gc;
          of32[idx] = res[idx] + vv;
        } else if (EPI==EPI_GELU){
          obf[(size_t)gr*N + gc] = f2b(gelu_t(vv + bias[gc]));
        } else {
          const size_t idx = (size_t)gr*N + gc;
          of32[idx] = of32[idx] + vv + (bias ? bias[gc] : 0.f);
        }
      }
    }
  }
}

// ------- per-segment memory contribution (MFMA): Mseg = elu(K)^T V, zseg -------
__global__ __launch_bounds__(256)
void memseg_k(const u16* __restrict__ kb, const u16* __restrict__ vb,
              float* __restrict__ Mseg, float* __restrict__ zseg)
{
  const int bid = blockIdx.x;           // b*64 + h*8 + seg
  const int seg = bid & 7, h = (bid>>3)&7, b = bid>>6;
  __shared__ __align__(16) u16 Kt[128*64];   // [dk][s] swizzled
  __shared__ __align__(16) u16 Vt[128*64];   // [dv][s] swizzled
  const int t=threadIdx.x, w=t>>6, lane=t&63, c=lane&15, g=lane>>4;

  f32x4 acc[2][8];
  f32x4 zacc[2];
  const f32x4 zzero = {0.f,0.f,0.f,0.f};
  #pragma unroll
  for (int d=0;d<2;d++){ zacc[d]=zzero;
    #pragma unroll
    for (int j=0;j<8;j++) acc[d][j]=zzero; }
  bf16x8 bones;
  { u16 tmp[8];
    #pragma unroll
    for (int e=0;e<8;e++) tmp[e] = (c==0) ? (u16)0x3F80 : (u16)0;
    bones = __builtin_bit_cast(bf16x8, *(uint4*)tmp); }

  for (int s0=0; s0<512; s0+=64){
    __syncthreads();
    {
      const int s = lane, dk0 = w<<5;
      const size_t grow = ((size_t)b*4096 + seg*512 + s0 + s)*1024 + h*128 + dk0;
      #pragma unroll
      for (int jj=0;jj<4;jj++){
        float kf[8], vf[8];
        unpack8(*(const uint4*)(kb + grow + jj*8), kf);
        unpack8(*(const uint4*)(vb + grow + jj*8), vf);
        #pragma unroll
        for (int e=0;e<8;e++){
          const int dk = dk0 + jj*8 + e;
          const float ek = kf[e]>0.f ? kf[e]+1.f : __expf(kf[e]);   // elu+1
          Kt[(dk<<6) + (s ^ ((dk&7)<<3))] = f2b(ek);
          Vt[(dk<<6) + (s ^ ((dk&7)<<3))] = f2b(vf[e]);
        }
      }
    }
    __syncthreads();
    #pragma unroll
    for (int ks=0;ks<2;ks++){
      const int kc = (ks<<5) + (g<<3);
      const bf16x8 a0 = *(const bf16x8*)&Kt[((((w<<1)  )*16 + c)<<6) + (kc ^ ((c&7)<<3))];
      const bf16x8 a1 = *(const bf16x8*)&Kt[((((w<<1)+1)*16 + c)<<6) + (kc ^ ((c&7)<<3))];
      zacc[0] = __builtin_amdgcn_mfma_f32_16x16x32_bf16(a0, bones, zacc[0], 0,0,0);
      zacc[1] = __builtin_amdgcn_mfma_f32_16x16x32_bf16(a1, bones, zacc[1], 0,0,0);
      #pragma unroll
      for (int j=0;j<8;j++){
        const bf16x8 bv = *(const bf16x8*)&Vt[(((j<<4) + c)<<6) + (kc ^ ((c&7)<<3))];
        acc[0][j] = __builtin_amdgcn_mfma_f32_16x16x32_bf16(a0, bv, acc[0][j], 0,0,0);
        acc[1][j] = __builtin_amdgcn_mfma_f32_16x16x32_bf16(a1, bv, acc[1][j], 0,0,0);
      }
    }
  }
  const size_t mb = (size_t)bid*16384;
  #pragma unroll
  for (int d=0;d<2;d++){
    const int dk = ((w<<1)+d)*16 + (g<<2);
    #pragma unroll
    for (int j=0;j<8;j++)
      #pragma unroll
      for (int r=0;r<4;r++)
        Mseg[mb + (size_t)(dk + r)*128 + (j<<4) + c] = acc[d][j][r];
    if (c==0){
      #pragma unroll
      for (int r=0;r<4;r++) zseg[(size_t)bid*128 + dk + r] = zacc[d][r];
    }
  }
}

// --- prefix scan over segments -> memBT (TRANSPOSED [dv][kd], bf16), zB ---
__global__ __launch_bounds__(256)
void scan_k(const float* __restrict__ Mseg, const float* __restrict__ zseg,
            u16* __restrict__ memBT, float* __restrict__ zB)
{
  const int bh = blockIdx.x >> 3, oct = blockIdx.x & 7;
  const int t = threadIdx.x;
  const int dv = (oct<<4) + (t&15);
  const int kd0 = (t>>4)<<3;
  float run[8];
  #pragma unroll
  for (int i=0;i<8;i++) run[i]=0.f;
  for (int seg=0; seg<8; seg++){
    const size_t base = ((size_t)bh*8 + seg)*16384;
    u16 tmp[8];
    #pragma unroll
    for (int i=0;i<8;i++) tmp[i] = f2b(run[i]);
    *(uint4*)(memBT + base + (size_t)dv*128 + kd0) = *(const uint4*)tmp;
    #pragma unroll
    for (int i=0;i<8;i++) run[i] += Mseg[base + (size_t)(kd0+i)*128 + dv];
  }
  if (oct==0 && t < 128){
    float zr = 1.f/128.f;
    for (int seg=0; seg<8; seg++){
      const size_t base = ((size_t)bh*8 + seg)*128;
      zB[base + t] = zr;
      zr += zseg[base + t];
    }
  }
}

// --- flash local attention (MFMA) + fused retrieval, low-pressure epilogue ---
__global__ __launch_bounds__(256,2)
void attn_k(const u16* __restrict__ qb, const u16* __restrict__ kb,
            const u16* __restrict__ vb, const u16* __restrict__ memBT,
            const float* __restrict__ zB, const float* __restrict__ betas,
            u16* __restrict__ attc)
{
  const int bid = blockIdx.x;
  const int s = bid & 255, rt = 7 - (bid >> 8);
  const int seg = s&7, h=(s>>3)&7, b=s>>6;
  __shared__ __align__(16) u16 smem[16384];  // Ks[0,8192)+Vt[8192,16384); epi: memT
  __shared__ __align__(16) u16 Ps[4096];     // P 64x64 swizzled; epi: z overlay
  u16* Ks = smem;
  u16* Vt = smem + 8192;
  float* zP = (float*)Ps;
  const int t=threadIdx.x, w=t>>6, lane=t&63, c=lane&15, g=lane>>4;
  const size_t base = ((size_t)b*4096 + seg*512)*1024 + h*128;

  bf16x8 af[4];
  {
    const u16* qsrc = qb + base + (size_t)(rt*64 + (w<<4) + c)*1024 + (g<<3);
    #pragma unroll
    for (int ks=0;ks<4;ks++) af[ks] = *(const bf16x8*)(qsrc + ks*32);
  }
  f32x4 acc[8];
  #pragma unroll
  for (int f=0;f<8;f++) acc[f] = (f32x4){0.f,0.f,0.f,0.f};
  float m_run[4], l_run[4];
  #pragma unroll
  for (int r=0;r<4;r++){ m_run[r] = -1e30f; l_run[r] = 0.f; }
  const float scl = 0.08838834764831845f;

  for (int kc=0; kc<=rt; kc++){
    __syncthreads();
    #pragma unroll
    for (int j=0;j<4;j++){
      const int row = (j<<2) + (lane>>4);
      const u16* src = kb + base + (size_t)(kc*64 + (w<<4) + row)*1024
                       + ((size_t)((lane&15) ^ (((w<<4)+row)&7)) << 3);
      g2l16(src, Ks + (((w<<4)+(j<<2))<<7));
    }
    {
      const int kr = lane, d0 = w<<5;
      const u16* vsrc = vb + base + (size_t)(kc*64+kr)*1024 + d0;
      #pragma unroll
      for (int jj=0;jj<4;jj++){
        const uint4 vv = *(const uint4*)(vsrc + jj*8);
        u16 tmp[8]; *(uint4*)tmp = vv;
        #pragma unroll
        for (int e=0;e<8;e++){
          const int dv = d0 + jj*8 + e;
          Vt[(dv<<6) + (kr ^ ((dv&7)<<3))] = tmp[e];
        }
      }
    }
    __syncthreads();
    f32x4 sv[4];
    #pragma unroll
    for (int j=0;j<4;j++) sv[j] = (f32x4){0.f,0.f,0.f,0.f};
    #pragma unroll
    for (int ks=0;ks<4;ks++)
      #pragma unroll
      for (int j=0;j<4;j++){
        const bf16x8 bk = *(const bf16x8*)&Ks[(((j<<4)+c)<<7) + ((((ks<<2)|g) ^ (c&7))<<3)];
        sv[j] = __builtin_amdgcn_mfma_f32_16x16x32_bf16(af[ks], bk, sv[j], 0,0,0);
      }
    const bool diag = (kc==rt);
    float p[4][4], rm[4], rsum[4];
    #pragma unroll
    for (int r=0;r<4;r++){
      float mx = -1e30f;
      #pragma unroll
      for (int j=0;j<4;j++){
        float svv = sv[j][r]*scl;
        if (diag && ((j<<4)+c) > ((w<<4) + (g<<2) + r)) svv = -1e30f;
        p[j][r] = svv;
        mx = fmaxf(mx, svv);
      }
      rm[r] = mx;
    }
    #pragma unroll
    for (int o=1;o<16;o<<=1)
      #pragma unroll
      for (int r=0;r<4;r++) rm[r] = fmaxf(rm[r], __shfl_xor(rm[r], o));
    #pragma unroll
    for (int r=0;r<4;r++){
      const float mn = fmaxf(m_run[r], rm[r]);
      const float sc = __expf(m_run[r] - mn);
      m_run[r] = mn;
      float sum = 0.f;
      #pragma unroll
      for (int j=0;j<4;j++){ p[j][r] = __expf(p[j][r]-mn); sum += p[j][r]; }
      rsum[r] = sum;
      l_run[r] *= sc;
      #pragma unroll
      for (int f=0;f<8;f++) acc[f][r] *= sc;
    }
    #pragma unroll
    for (int o=1;o<16;o<<=1)
      #pragma unroll
      for (int r=0;r<4;r++) rsum[r] += __shfl_xor(rsum[r], o);
    #pragma unroll
    for (int r=0;r<4;r++) l_run[r] += rsum[r];
    #pragma unroll
    for (int j=0;j<4;j++)
      #pragma unroll
      for (int r=0;r<4;r++){
        const int prow = (w<<4)+(g<<2)+r;
        Ps[(prow<<6) + (((j<<4)+c) ^ ((prow&7)<<3))] = f2b(p[j][r]);
      }
    #pragma unroll
    for (int ks2=0; ks2<2; ks2++){
      const bf16x8 pa = *(const bf16x8*)&Ps[(((w<<4)+c)<<6) + ((((ks2<<2)|g) ^ (c&7))<<3)];
      #pragma unroll
      for (int f=0;f<8;f++){
        const int dv = (f<<4)+c;
        const bf16x8 bv = *(const bf16x8*)&Vt[(dv<<6) + ((((ks2<<2)|g) ^ (c&7))<<3)];
        acc[f] = __builtin_amdgcn_mfma_f32_16x16x32_bf16(pa, bv, acc[f], 0,0,0);
      }
    }
  }
  // ---- epilogue: memT+z stage ----
  __syncthreads();
  {
    const size_t mbase = (((size_t)b*8+h)*8+seg) << 14;
    #pragma unroll
    for (int i=0;i<8;i++){
      const int row = (i<<2) + (lane>>4);
      const u16* src = memBT + mbase + ((size_t)((w<<5)+row)<<7)
                       + ((size_t)((lane&15) ^ (((w<<5)+row)&7)) << 3);
      g2l16(src, smem + (((w<<5)+(i<<2))<<7));
    }
    if (t < 128) zP[t] = zB[((((size_t)b*8+h)*8+seg)<<7) + t];
  }
  __syncthreads();
  // elu(Q)+1 in place (af -> sq fragments) + fp32 z-dot partial
  float dpart = 0.f;
  #pragma unroll
  for (int ks=0;ks<4;ks++){
    float f[8]; unpack8(__builtin_bit_cast(uint4, af[ks]), f);
    #pragma unroll
    for (int e=0;e<8;e++){
      f[e] = f[e]>0.f ? f[e]+1.f : __expf(f[e]);
      dpart += f[e] * zP[ks*32 + (g<<3) + e];
    }
    af[ks] = __builtin_bit_cast(bf16x8, pack8(f));
  }
  dpart += __shfl_xor(dpart, 16);
  dpart += __shfl_xor(dpart, 32);        // = den of q-row (w*16+c), all g
  float den[4];
  #pragma unroll
  for (int r=0;r<4;r++) den[r] = 1.f / __shfl(dpart, (g<<2)+r);
  // retrieval folded per-f + gated combine + direct stores
  #pragma unroll 2
  for (int f=0;f<8;f++){
    f32x4 nf = {0.f,0.f,0.f,0.f};
    #pragma unroll
    for (int ks=0;ks<4;ks++){
      const bf16x8 bm = *(const bf16x8*)&smem[(((f<<4)+c)<<7) + ((((ks<<2)|g) ^ (c&7))<<3)];
      nf = __builtin_amdgcn_mfma_f32_16x16x32_bf16(af[ks], bm, nf, 0,0,0);
    }
    const float bv = betas[(h<<7) + (f<<4) + c];
    const float gate = 1.f/(1.f+__expf(-bv));
    #pragma unroll
    for (int r=0;r<4;r++){
      const size_t idx = base + (size_t)(rt*64 + (w<<4) + (g<<2) + r)*1024 + (f<<4) + c;
      const float att = acc[f][r] / l_run[r];
      const float am  = nf[r] * den[r];
      attc[idx] = f2b(gate*am + (1.f-gate)*att);
    }
  }
}

extern "C" void kernel_launch(void* const* d_in, const int* in_sizes, int n_in,
                              void* d_out, int out_size, void* d_ws, size_t ws_size,
                              hipStream_t stream)
{
  (void)in_sizes; (void)n_in; (void)out_size; (void)ws_size;
  const float* x    = (const float*)d_in[0];
  const float* ln_g = (const float*)d_in[1];
  const float* ln_b = (const float*)d_in[2];
  const float* Wq   = (const float*)d_in[3];
  const float* Wk   = (const float*)d_in[4];
  const float* Wv   = (const float*)d_in[5];
  const float* Wo   = (const float*)d_in[6];
  const float* betas= (const float*)d_in[7];
  const float* w1   = (const float*)d_in[8];
  const float* b1   = (const float*)d_in[9];
  const float* w2   = (const float*)d_in[10];
  const float* b2   = (const float*)d_in[11];
  float* out = (float*)d_out;

  // ---- workspace: 96 MB qkv + 24 MB bf16 weights = 120 MB ----
  char* ws = (char*)d_ws;
  const size_t MB = 1048576;
  u16* qb  = (u16*)(ws);              // qb -> at (in-place) -> FF hidden (w/ kb)
  u16* kb  = (u16*)(ws + 32*MB);      // kb -> FF hidden (second half)
  u16* vb  = (u16*)(ws + 64*MB);      // vb -> h2 (LN2 out)
  u16* Wqkv= (u16*)(ws + 96*MB);      // [3072][1024] bf16 (Wq|Wk|Wv rows)
  u16* Wob = (u16*)(ws + 102*MB);
  u16* w1b = (u16*)(ws + 104*MB);     // [4096][1024], 8 MB
  u16* w2b = (u16*)(ws + 112*MB);     // [1024][4096], 8 MB
  // ---- d_out doubles as scratch before the Wo GEMM overwrites it ----
  char* ob = (char*)d_out;
  u16*   h    = (u16*)ob;             // 32 MB bf16 (LN1 out; dead after QKV)
  float* Mseg = (float*)(ob + 32*MB); // 16 MB
  u16*   memBT= (u16*)  (ob + 48*MB); // 8 MB
  float* zseg = (float*)(ob + 56*MB); // 128 KB
  float* zB   = (float*)(ob + 56*MB + 131072);
  u16*   at   = qb;
  u16*   h2   = vb;                   // LN2 out lives in vb (free after attn)
  u16*   gb2  = qb;                   // FF hidden chunk: 64 MB spanning qb+kb

  // weight conversion (fp32 [K][N] -> bf16 [N][K])
  wconv_k<<<dim3(32,32),256,0,stream>>>(Wq, Wqkv,              1024,1024);
  wconv_k<<<dim3(32,32),256,0,stream>>>(Wk, Wqkv+1024*1024,    1024,1024);
  wconv_k<<<dim3(32,32),256,0,stream>>>(Wv, Wqkv+2*1024*1024,  1024,1024);
  wconv_k<<<dim3(32,32),256,0,stream>>>(Wo, Wob, 1024,1024);
  wconv_k<<<dim3(128,32),256,0,stream>>>(w1, w1b, 1024,4096);
  wconv_k<<<dim3(32,128),256,0,stream>>>(w2, w2b, 4096,1024);

  ln_k<<<16384,256,0,stream>>>(x, ln_g, ln_b, h);
  // fused QKV: [16384,1024] x [1024,3072] -> qb|kb|vb
  gemm3_k<EPI_QKV><<<dim3(12,64),512,0,stream>>>(h, Wqkv, 1024,1024,1024, 3072,
                                                 qb, nullptr, nullptr, nullptr);
  memseg_k<<<256,256,0,stream>>>(kb, vb, Mseg, zseg);
  scan_k<<<256,256,0,stream>>>(Mseg, zseg, memBT, zB);
  attn_k<<<2048,256,0,stream>>>(qb, kb, vb, memBT, zB, betas, at);
  gemm3_k<EPI_WO><<<dim3(4,64),512,0,stream>>>(at, Wob, 1024,1024,1024, 1024,
                                               nullptr, out, x, nullptr);
  ln_k<<<16384,256,0,stream>>>(out, ln_g, ln_b, h2);
  // FF chunked over HIDDEN dim: 2 chunks of 2048 cols (hidden chunk = 64 MB in qb+kb)
  for (int cc = 0; cc < 2; cc++){
    gemm3_k<EPI_GELU><<<dim3(8,64),512,0,stream>>>(h2, w1b + (size_t)cc*2048*1024,
                                                   1024,1024,1024, 2048,
                                                   gb2, nullptr, nullptr, b1 + cc*2048);
    gemm3_k<EPI_FF2><<<dim3(4,64),512,0,stream>>>(gb2, w2b + (size_t)cc*2048,
                                                  2048,2048,4096, 1024,
                                                  nullptr, out, nullptr,
                                                  cc==0 ? b2 : nullptr);
  }
}

// Round 15
// 778.111 us; speedup vs baseline: 1.0080x; 1.0080x over previous
//
#include <hip/hip_runtime.h>

typedef unsigned short u16;
typedef unsigned int   u32;
typedef float f32x4 __attribute__((ext_vector_type(4)));
typedef short bf16x8 __attribute__((ext_vector_type(8)));

#define DEV static __device__ __forceinline__

DEV u16 f2b(float f){
  u32 u = __builtin_bit_cast(u32, f);
  return (u16)((u + 0x7fffu + ((u >> 16) & 1u)) >> 16);
}
DEV float b2f(u16 h){ u32 u = ((u32)h) << 16; return __builtin_bit_cast(float, u); }
DEV u32 pack2(float a, float b){ return (u32)f2b(a) | ((u32)f2b(b) << 16); }
DEV uint4 pack8(const float* f){
  uint4 r; r.x = pack2(f[0],f[1]); r.y = pack2(f[2],f[3]);
  r.z = pack2(f[4],f[5]); r.w = pack2(f[6],f[7]); return r;
}
DEV void unpack8(uint4 u, float* f){
  f[0]=b2f((u16)(u.x&0xffffu)); f[1]=b2f((u16)(u.x>>16));
  f[2]=b2f((u16)(u.y&0xffffu)); f[3]=b2f((u16)(u.y>>16));
  f[4]=b2f((u16)(u.z&0xffffu)); f[5]=b2f((u16)(u.z>>16));
  f[6]=b2f((u16)(u.w&0xffffu)); f[7]=b2f((u16)(u.w>>16));
}
// gelu-tanh via sigmoid identity: 0.5x(1+tanh(z)) = x*sigma(2z); hardware v_exp
DEV float gelu_t(float x){
  const float z2 = 1.5957691216057308f*(x + 0.044715f*x*x*x);
  return x / (1.f + __expf(-z2));
}
// async global->LDS, 16B per lane; LDS dest = wave-uniform base + lane*16
DEV void g2l16(const u16* g, u16* l){
  __builtin_amdgcn_global_load_lds(
    (const __attribute__((address_space(1))) u32*)g,
    (__attribute__((address_space(3))) u32*)l, 16, 0, 0);
}

// ---------------- LayerNorm: fp32 [rows][1024] -> bf16 ----------------
__global__ __launch_bounds__(256)
void ln_k(const float* __restrict__ x, const float* __restrict__ gamma,
          const float* __restrict__ beta, u16* __restrict__ out)
{
  const int row = blockIdx.x;
  const int t = threadIdx.x;
  const float4 v = ((const float4*)(x + (size_t)row*1024))[t];
  float s  = v.x+v.y+v.z+v.w;
  float ss = v.x*v.x+v.y*v.y+v.z*v.z+v.w*v.w;
  #pragma unroll
  for (int o=32;o;o>>=1){ s += __shfl_xor(s,o); ss += __shfl_xor(ss,o); }
  __shared__ float rs[4], rq[4];
  if ((t&63)==0){ rs[t>>6]=s; rq[t>>6]=ss; }
  __syncthreads();
  s  = rs[0]+rs[1]+rs[2]+rs[3];
  ss = rq[0]+rq[1]+rq[2]+rq[3];
  const float mean = s*(1.f/1024.f);
  const float var  = ss*(1.f/1024.f) - mean*mean;
  const float inv  = rsqrtf(var + 1e-5f);
  const float4 g4 = ((const float4*)gamma)[t];
  const float4 b4 = ((const float4*)beta)[t];
  float o[4];
  o[0]=(v.x-mean)*inv*g4.x+b4.x; o[1]=(v.y-mean)*inv*g4.y+b4.y;
  o[2]=(v.z-mean)*inv*g4.z+b4.z; o[3]=(v.w-mean)*inv*g4.w+b4.w;
  uint2 w; w.x = pack2(o[0],o[1]); w.y = pack2(o[2],o[3]);
  *(uint2*)(out + (size_t)row*1024 + t*4) = w;
}

// ------------- weight conversion: W [K][N] fp32 -> WT [N][K] bf16 -------------
__global__ __launch_bounds__(256)
void wconv_k(const float* __restrict__ W, u16* __restrict__ WT, int K, int N)
{
  __shared__ float tile[32][33];
  const int k0 = blockIdx.y<<5, n0 = blockIdx.x<<5;
  const int tx = threadIdx.x & 31, ty = threadIdx.x >> 5;   // 32 x 8
  #pragma unroll
  for (int r=0;r<32;r+=8)
    tile[ty+r][tx] = W[(size_t)(k0+ty+r)*N + n0+tx];
  __syncthreads();
  #pragma unroll
  for (int r=0;r<32;r+=8)
    WT[(size_t)(n0+ty+r)*K + k0+tx] = f2b(tile[tx][ty+r]);
}

// ---- bf16 MFMA GEMM, 256x256 tile, BK=32, dbuf + early-issue + XOR swizzle ----
// 8 waves as 2(M) x 4(N); per-wave output 128x64 (8x4 16x16 frags).
// (512,1): reg demand ~216 (128 acc + ~88 arch) needs the full 512 budget;
// r14's unhinted build capped arch at 88 and spilled (~+34MB FETCH and WRITE).
#define EPI_QKV  0
#define EPI_WO   1
#define EPI_GELU 2
#define EPI_FF2  3

template<int EPI>
__global__ __launch_bounds__(512,1)
void gemm3_k(const u16* __restrict__ A, const u16* __restrict__ BT,
             int K, int lda, int ldb, int N,
             u16* __restrict__ obf, float* __restrict__ of32,
             const float* __restrict__ res, const float* __restrict__ bias)
{
  __shared__ __align__(16) u16 SA[2*8192];    // [buf][256 rows][32 k]
  __shared__ __align__(16) u16 SB[2*8192];
  const int t = threadIdx.x, wid = t>>6, lane = t&63;
  const int c = lane&15, g = lane>>4;
  const int wm = wid>>2, wn = wid&3;
  const int nwg = gridDim.x*gridDim.y;
  const int lb = blockIdx.y*gridDim.x + blockIdx.x;
  const int nl = (lb&7)*(nwg>>3) + (lb>>3);
  const int bx = nl % gridDim.x, by = nl / gridDim.x;
  const int m0 = by<<8, n0 = bx<<8;
  // staging: wave-load l (l=0,1) covers rows wid*32 + l*16 + (lane>>2), chunk lane&3
  const int srow = lane>>2;
  const int schunk = ((lane&3) ^ (srow&3))<<3;        // inverse-swizzled source
  const u16* aSrc0 = A  + (size_t)(m0 + (wid<<5) + srow)*lda + schunk;
  const u16* bSrc0 = BT + (size_t)(n0 + (wid<<5) + srow)*ldb + schunk;
  const u16* aSrc1 = aSrc0 + (size_t)16*lda;
  const u16* bSrc1 = bSrc0 + (size_t)16*ldb;
  const int kx = (g<<3) ^ ((c&3)<<3);                 // swizzled frag read

  f32x4 acc[8][4];
  #pragma unroll
  for (int i=0;i<8;i++)
    #pragma unroll
    for (int j=0;j<4;j++) acc[i][j] = (f32x4){0.f,0.f,0.f,0.f};

  g2l16(aSrc0, &SA[(wid<<1)<<9]);
  g2l16(aSrc1, &SA[((wid<<1)|1)<<9]);
  g2l16(bSrc0, &SB[(wid<<1)<<9]);
  g2l16(bSrc1, &SB[((wid<<1)|1)<<9]);
  __syncthreads();

  const int nt = K >> 5;
  for (int tt = 0; tt < nt; ++tt){
    const int cur = tt & 1;
    if (tt + 1 < nt){
      const int ko = (tt+1) << 5;
      const int db = (cur^1)<<13;
      g2l16(aSrc0 + ko, &SA[db + ((wid<<1)<<9)]);
      g2l16(aSrc1 + ko, &SA[db + (((wid<<1)|1)<<9)]);
      g2l16(bSrc0 + ko, &SB[db + ((wid<<1)<<9)]);
      g2l16(bSrc1 + ko, &SB[db + (((wid<<1)|1)<<9)]);
    }
    bf16x8 af[8], bf[4];
    #pragma unroll
    for (int i=0;i<8;i++)
      af[i] = *(const bf16x8*)&SA[(cur<<13) + ((wm<<7)+(i<<4)+c)*32 + kx];
    #pragma unroll
    for (int j=0;j<4;j++)
      bf[j] = *(const bf16x8*)&SB[(cur<<13) + ((wn<<6)+(j<<4)+c)*32 + kx];
    #pragma unroll
    for (int i=0;i<8;i++)
      #pragma unroll
      for (int j=0;j<4;j++)
        acc[i][j] = __builtin_amdgcn_mfma_f32_16x16x32_bf16(af[i], bf[j], acc[i][j], 0,0,0);
    __syncthreads();
  }

  #pragma unroll
  for (int i=0;i<8;i++){
    const int gr0 = m0 + (wm<<7) + (i<<4) + (g<<2);
    #pragma unroll
    for (int j=0;j<4;j++){
      const int gc = n0 + (wn<<6) + (j<<4) + c;
      #pragma unroll
      for (int r=0;r<4;r++){
        const int gr = gr0 + r;
        const float vv = acc[i][j][r];
        if (EPI==EPI_QKV){
          obf[((size_t)(gc>>10)<<24) + (size_t)gr*1024 + (gc&1023)] = f2b(vv);
        } else if (EPI==EPI_WO){
          const size_t idx = (size_t)gr*N + gc;
          of32[idx] = res[idx] + vv;
        } else if (EPI==EPI_GELU){
          obf[(size_t)gr*N + gc] = f2b(gelu_t(vv + bias[gc]));
        } else {
          const size_t idx = (size_t)gr*N + gc;
          of32[idx] = of32[idx] + vv + (bias ? bias[gc] : 0.f);
        }
      }
    }
  }
}

// ------- per-segment memory contribution (MFMA): Mseg = elu(K)^T V, zseg -------
__global__ __launch_bounds__(256)
void memseg_k(const u16* __restrict__ kb, const u16* __restrict__ vb,
              float* __restrict__ Mseg, float* __restrict__ zseg)
{
  const int bid = blockIdx.x;           // b*64 + h*8 + seg
  const int seg = bid & 7, h = (bid>>3)&7, b = bid>>6;
  __shared__ __align__(16) u16 Kt[128*64];   // [dk][s] swizzled
  __shared__ __align__(16) u16 Vt[128*64];   // [dv][s] swizzled
  const int t=threadIdx.x, w=t>>6, lane=t&63, c=lane&15, g=lane>>4;

  f32x4 acc[2][8];
  f32x4 zacc[2];
  const f32x4 zzero = {0.f,0.f,0.f,0.f};
  #pragma unroll
  for (int d=0;d<2;d++){ zacc[d]=zzero;
    #pragma unroll
    for (int j=0;j<8;j++) acc[d][j]=zzero; }
  bf16x8 bones;
  { u16 tmp[8];
    #pragma unroll
    for (int e=0;e<8;e++) tmp[e] = (c==0) ? (u16)0x3F80 : (u16)0;
    bones = __builtin_bit_cast(bf16x8, *(uint4*)tmp); }

  for (int s0=0; s0<512; s0+=64){
    __syncthreads();
    {
      const int s = lane, dk0 = w<<5;
      const size_t grow = ((size_t)b*4096 + seg*512 + s0 + s)*1024 + h*128 + dk0;
      #pragma unroll
      for (int jj=0;jj<4;jj++){
        float kf[8], vf[8];
        unpack8(*(const uint4*)(kb + grow + jj*8), kf);
        unpack8(*(const uint4*)(vb + grow + jj*8), vf);
        #pragma unroll
        for (int e=0;e<8;e++){
          const int dk = dk0 + jj*8 + e;
          const float ek = kf[e]>0.f ? kf[e]+1.f : __expf(kf[e]);   // elu+1
          Kt[(dk<<6) + (s ^ ((dk&7)<<3))] = f2b(ek);
          Vt[(dk<<6) + (s ^ ((dk&7)<<3))] = f2b(vf[e]);
        }
      }
    }
    __syncthreads();
    #pragma unroll
    for (int ks=0;ks<2;ks++){
      const int kc = (ks<<5) + (g<<3);
      const bf16x8 a0 = *(const bf16x8*)&Kt[((((w<<1)  )*16 + c)<<6) + (kc ^ ((c&7)<<3))];
      const bf16x8 a1 = *(const bf16x8*)&Kt[((((w<<1)+1)*16 + c)<<6) + (kc ^ ((c&7)<<3))];
      zacc[0] = __builtin_amdgcn_mfma_f32_16x16x32_bf16(a0, bones, zacc[0], 0,0,0);
      zacc[1] = __builtin_amdgcn_mfma_f32_16x16x32_bf16(a1, bones, zacc[1], 0,0,0);
      #pragma unroll
      for (int j=0;j<8;j++){
        const bf16x8 bv = *(const bf16x8*)&Vt[(((j<<4) + c)<<6) + (kc ^ ((c&7)<<3))];
        acc[0][j] = __builtin_amdgcn_mfma_f32_16x16x32_bf16(a0, bv, acc[0][j], 0,0,0);
        acc[1][j] = __builtin_amdgcn_mfma_f32_16x16x32_bf16(a1, bv, acc[1][j], 0,0,0);
      }
    }
  }
  const size_t mb = (size_t)bid*16384;
  #pragma unroll
  for (int d=0;d<2;d++){
    const int dk = ((w<<1)+d)*16 + (g<<2);
    #pragma unroll
    for (int j=0;j<8;j++)
      #pragma unroll
      for (int r=0;r<4;r++)
        Mseg[mb + (size_t)(dk + r)*128 + (j<<4) + c] = acc[d][j][r];
    if (c==0){
      #pragma unroll
      for (int r=0;r<4;r++) zseg[(size_t)bid*128 + dk + r] = zacc[d][r];
    }
  }
}

// --- prefix scan over segments -> memBT (TRANSPOSED [dv][kd], bf16), zB ---
__global__ __launch_bounds__(256)
void scan_k(const float* __restrict__ Mseg, const float* __restrict__ zseg,
            u16* __restrict__ memBT, float* __restrict__ zB)
{
  const int bh = blockIdx.x >> 3, oct = blockIdx.x & 7;
  const int t = threadIdx.x;
  const int dv = (oct<<4) + (t&15);
  const int kd0 = (t>>4)<<3;
  float run[8];
  #pragma unroll
  for (int i=0;i<8;i++) run[i]=0.f;
  for (int seg=0; seg<8; seg++){
    const size_t base = ((size_t)bh*8 + seg)*16384;
    u16 tmp[8];
    #pragma unroll
    for (int i=0;i<8;i++) tmp[i] = f2b(run[i]);
    *(uint4*)(memBT + base + (size_t)dv*128 + kd0) = *(const uint4*)tmp;
    #pragma unroll
    for (int i=0;i<8;i++) run[i] += Mseg[base + (size_t)(kd0+i)*128 + dv];
  }
  if (oct==0 && t < 128){
    float zr = 1.f/128.f;
    for (int seg=0; seg<8; seg++){
      const size_t base = ((size_t)bh*8 + seg)*128;
      zB[base + t] = zr;
      zr += zseg[base + t];
    }
  }
}

// --- flash local attention (MFMA) + fused retrieval, low-pressure epilogue ---
__global__ __launch_bounds__(256,2)
void attn_k(const u16* __restrict__ qb, const u16* __restrict__ kb,
            const u16* __restrict__ vb, const u16* __restrict__ memBT,
            const float* __restrict__ zB, const float* __restrict__ betas,
            u16* __restrict__ attc)
{
  const int bid = blockIdx.x;
  const int s = bid & 255, rt = 7 - (bid >> 8);
  const int seg = s&7, h=(s>>3)&7, b=s>>6;
  __shared__ __align__(16) u16 smem[16384];  // Ks[0,8192)+Vt[8192,16384); epi: memT
  __shared__ __align__(16) u16 Ps[4096];     // P 64x64 swizzled; epi: z overlay
  u16* Ks = smem;
  u16* Vt = smem + 8192;
  float* zP = (float*)Ps;
  const int t=threadIdx.x, w=t>>6, lane=t&63, c=lane&15, g=lane>>4;
  const size_t base = ((size_t)b*4096 + seg*512)*1024 + h*128;

  bf16x8 af[4];
  {
    const u16* qsrc = qb + base + (size_t)(rt*64 + (w<<4) + c)*1024 + (g<<3);
    #pragma unroll
    for (int ks=0;ks<4;ks++) af[ks] = *(const bf16x8*)(qsrc + ks*32);
  }
  f32x4 acc[8];
  #pragma unroll
  for (int f=0;f<8;f++) acc[f] = (f32x4){0.f,0.f,0.f,0.f};
  float m_run[4], l_run[4];
  #pragma unroll
  for (int r=0;r<4;r++){ m_run[r] = -1e30f; l_run[r] = 0.f; }
  const float scl = 0.08838834764831845f;

  for (int kc=0; kc<=rt; kc++){
    __syncthreads();
    #pragma unroll
    for (int j=0;j<4;j++){
      const int row = (j<<2) + (lane>>4);
      const u16* src = kb + base + (size_t)(kc*64 + (w<<4) + row)*1024
                       + ((size_t)((lane&15) ^ (((w<<4)+row)&7)) << 3);
      g2l16(src, Ks + (((w<<4)+(j<<2))<<7));
    }
    {
      const int kr = lane, d0 = w<<5;
      const u16* vsrc = vb + base + (size_t)(kc*64+kr)*1024 + d0;
      #pragma unroll
      for (int jj=0;jj<4;jj++){
        const uint4 vv = *(const uint4*)(vsrc + jj*8);
        u16 tmp[8]; *(uint4*)tmp = vv;
        #pragma unroll
        for (int e=0;e<8;e++){
          const int dv = d0 + jj*8 + e;
          Vt[(dv<<6) + (kr ^ ((dv&7)<<3))] = tmp[e];
        }
      }
    }
    __syncthreads();
    f32x4 sv[4];
    #pragma unroll
    for (int j=0;j<4;j++) sv[j] = (f32x4){0.f,0.f,0.f,0.f};
    #pragma unroll
    for (int ks=0;ks<4;ks++)
      #pragma unroll
      for (int j=0;j<4;j++){
        const bf16x8 bk = *(const bf16x8*)&Ks[(((j<<4)+c)<<7) + ((((ks<<2)|g) ^ (c&7))<<3)];
        sv[j] = __builtin_amdgcn_mfma_f32_16x16x32_bf16(af[ks], bk, sv[j], 0,0,0);
      }
    const bool diag = (kc==rt);
    float p[4][4], rm[4], rsum[4];
    #pragma unroll
    for (int r=0;r<4;r++){
      float mx = -1e30f;
      #pragma unroll
      for (int j=0;j<4;j++){
        float svv = sv[j][r]*scl;
        if (diag && ((j<<4)+c) > ((w<<4) + (g<<2) + r)) svv = -1e30f;
        p[j][r] = svv;
        mx = fmaxf(mx, svv);
      }
      rm[r] = mx;
    }
    #pragma unroll
    for (int o=1;o<16;o<<=1)
      #pragma unroll
      for (int r=0;r<4;r++) rm[r] = fmaxf(rm[r], __shfl_xor(rm[r], o));
    #pragma unroll
    for (int r=0;r<4;r++){
      const float mn = fmaxf(m_run[r], rm[r]);
      const float sc = __expf(m_run[r] - mn);
      m_run[r] = mn;
      float sum = 0.f;
      #pragma unroll
      for (int j=0;j<4;j++){ p[j][r] = __expf(p[j][r]-mn); sum += p[j][r]; }
      rsum[r] = sum;
      l_run[r] *= sc;
      #pragma unroll
      for (int f=0;f<8;f++) acc[f][r] *= sc;
    }
    #pragma unroll
    for (int o=1;o<16;o<<=1)
      #pragma unroll
      for (int r=0;r<4;r++) rsum[r] += __shfl_xor(rsum[r], o);
    #pragma unroll
    for (int r=0;r<4;r++) l_run[r] += rsum[r];
    #pragma unroll
    for (int j=0;j<4;j++)
      #pragma unroll
      for (int r=0;r<4;r++){
        const int prow = (w<<4)+(g<<2)+r;
        Ps[(prow<<6) + (((j<<4)+c) ^ ((prow&7)<<3))] = f2b(p[j][r]);
      }
    #pragma unroll
    for (int ks2=0; ks2<2; ks2++){
      const bf16x8 pa = *(const bf16x8*)&Ps[(((w<<4)+c)<<6) + ((((ks2<<2)|g) ^ (c&7))<<3)];
      #pragma unroll
      for (int f=0;f<8;f++){
        const int dv = (f<<4)+c;
        const bf16x8 bv = *(const bf16x8*)&Vt[(dv<<6) + ((((ks2<<2)|g) ^ (c&7))<<3)];
        acc[f] = __builtin_amdgcn_mfma_f32_16x16x32_bf16(pa, bv, acc[f], 0,0,0);
      }
    }
  }
  // ---- epilogue: memT+z stage ----
  __syncthreads();
  {
    const size_t mbase = (((size_t)b*8+h)*8+seg) << 14;
    #pragma unroll
    for (int i=0;i<8;i++){
      const int row = (i<<2) + (lane>>4);
      const u16* src = memBT + mbase + ((size_t)((w<<5)+row)<<7)
                       + ((size_t)((lane&15) ^ (((w<<5)+row)&7)) << 3);
      g2l16(src, smem + (((w<<5)+(i<<2))<<7));
    }
    if (t < 128) zP[t] = zB[((((size_t)b*8+h)*8+seg)<<7) + t];
  }
  __syncthreads();
  // elu(Q)+1 in place (af -> sq fragments) + fp32 z-dot partial
  float dpart = 0.f;
  #pragma unroll
  for (int ks=0;ks<4;ks++){
    float f[8]; unpack8(__builtin_bit_cast(uint4, af[ks]), f);
    #pragma unroll
    for (int e=0;e<8;e++){
      f[e] = f[e]>0.f ? f[e]+1.f : __expf(f[e]);
      dpart += f[e] * zP[ks*32 + (g<<3) + e];
    }
    af[ks] = __builtin_bit_cast(bf16x8, pack8(f));
  }
  dpart += __shfl_xor(dpart, 16);
  dpart += __shfl_xor(dpart, 32);        // = den of q-row (w*16+c), all g
  float den[4];
  #pragma unroll
  for (int r=0;r<4;r++) den[r] = 1.f / __shfl(dpart, (g<<2)+r);
  // retrieval folded per-f + gated combine + direct stores
  #pragma unroll 2
  for (int f=0;f<8;f++){
    f32x4 nf = {0.f,0.f,0.f,0.f};
    #pragma unroll
    for (int ks=0;ks<4;ks++){
      const bf16x8 bm = *(const bf16x8*)&smem[(((f<<4)+c)<<7) + ((((ks<<2)|g) ^ (c&7))<<3)];
      nf = __builtin_amdgcn_mfma_f32_16x16x32_bf16(af[ks], bm, nf, 0,0,0);
    }
    const float bv = betas[(h<<7) + (f<<4) + c];
    const float gate = 1.f/(1.f+__expf(-bv));
    #pragma unroll
    for (int r=0;r<4;r++){
      const size_t idx = base + (size_t)(rt*64 + (w<<4) + (g<<2) + r)*1024 + (f<<4) + c;
      const float att = acc[f][r] / l_run[r];
      const float am  = nf[r] * den[r];
      attc[idx] = f2b(gate*am + (1.f-gate)*att);
    }
  }
}

extern "C" void kernel_launch(void* const* d_in, const int* in_sizes, int n_in,
                              void* d_out, int out_size, void* d_ws, size_t ws_size,
                              hipStream_t stream)
{
  (void)in_sizes; (void)n_in; (void)out_size; (void)ws_size;
  const float* x    = (const float*)d_in[0];
  const float* ln_g = (const float*)d_in[1];
  const float* ln_b = (const float*)d_in[2];
  const float* Wq   = (const float*)d_in[3];
  const float* Wk   = (const float*)d_in[4];
  const float* Wv   = (const float*)d_in[5];
  const float* Wo   = (const float*)d_in[6];
  const float* betas= (const float*)d_in[7];
  const float* w1   = (const float*)d_in[8];
  const float* b1   = (const float*)d_in[9];
  const float* w2   = (const float*)d_in[10];
  const float* b2   = (const float*)d_in[11];
  float* out = (float*)d_out;

  // ---- workspace: 96 MB qkv + 24 MB bf16 weights = 120 MB ----
  char* ws = (char*)d_ws;
  const size_t MB = 1048576;
  u16* qb  = (u16*)(ws);              // qb -> at (in-place) -> FF hidden (w/ kb)
  u16* kb  = (u16*)(ws + 32*MB);      // kb -> FF hidden (second half)
  u16* vb  = (u16*)(ws + 64*MB);      // vb -> h2 (LN2 out)
  u16* Wqkv= (u16*)(ws + 96*MB);      // [3072][1024] bf16 (Wq|Wk|Wv rows)
  u16* Wob = (u16*)(ws + 102*MB);
  u16* w1b = (u16*)(ws + 104*MB);     // [4096][1024], 8 MB
  u16* w2b = (u16*)(ws + 112*MB);     // [1024][4096], 8 MB
  // ---- d_out doubles as scratch before the Wo GEMM overwrites it ----
  char* ob = (char*)d_out;
  u16*   h    = (u16*)ob;             // 32 MB bf16 (LN1 out; dead after QKV)
  float* Mseg = (float*)(ob + 32*MB); // 16 MB
  u16*   memBT= (u16*)  (ob + 48*MB); // 8 MB
  float* zseg = (float*)(ob + 56*MB); // 128 KB
  float* zB   = (float*)(ob + 56*MB + 131072);
  u16*   at   = qb;
  u16*   h2   = vb;                   // LN2 out lives in vb (free after attn)
  u16*   gb2  = qb;                   // FF hidden chunk: 64 MB spanning qb+kb

  // weight conversion (fp32 [K][N] -> bf16 [N][K])
  wconv_k<<<dim3(32,32),256,0,stream>>>(Wq, Wqkv,              1024,1024);
  wconv_k<<<dim3(32,32),256,0,stream>>>(Wk, Wqkv+1024*1024,    1024,1024);
  wconv_k<<<dim3(32,32),256,0,stream>>>(Wv, Wqkv+2*1024*1024,  1024,1024);
  wconv_k<<<dim3(32,32),256,0,stream>>>(Wo, Wob, 1024,1024);
  wconv_k<<<dim3(128,32),256,0,stream>>>(w1, w1b, 1024,4096);
  wconv_k<<<dim3(32,128),256,0,stream>>>(w2, w2b, 4096,1024);

  ln_k<<<16384,256,0,stream>>>(x, ln_g, ln_b, h);
  // fused QKV: [16384,1024] x [1024,3072] -> qb|kb|vb
  gemm3_k<EPI_QKV><<<dim3(12,64),512,0,stream>>>(h, Wqkv, 1024,1024,1024, 3072,
                                                 qb, nullptr, nullptr, nullptr);
  memseg_k<<<256,256,0,stream>>>(kb, vb, Mseg, zseg);
  scan_k<<<256,256,0,stream>>>(Mseg, zseg, memBT, zB);
  attn_k<<<2048,256,0,stream>>>(qb, kb, vb, memBT, zB, betas, at);
  gemm3_k<EPI_WO><<<dim3(4,64),512,0,stream>>>(at, Wob, 1024,1024,1024, 1024,
                                               nullptr, out, x, nullptr);
  ln_k<<<16384,256,0,stream>>>(out, ln_g, ln_b, h2);
  // FF chunked over HIDDEN dim: 2 chunks of 2048 cols (hidden chunk = 64 MB in qb+kb)
  for (int cc = 0; cc < 2; cc++){
    gemm3_k<EPI_GELU><<<dim3(8,64),512,0,stream>>>(h2, w1b + (size_t)cc*2048*1024,
                                                   1024,1024,1024, 2048,
                                                   gb2, nullptr, nullptr, b1 + cc*2048);
    gemm3_k<EPI_FF2><<<dim3(4,64),512,0,stream>>>(gb2, w2b + (size_t)cc*2048,
                                                  2048,2048,4096, 1024,
                                                  nullptr, out, nullptr,
                                                  cc==0 ? b2 : nullptr);
  }
}

// Round 17
// 726.243 us; speedup vs baseline: 1.0800x; 1.0714x over previous
//
#include <hip/hip_runtime.h>

typedef unsigned short u16;
typedef unsigned int   u32;
typedef float f32x4 __attribute__((ext_vector_type(4)));
typedef short bf16x8 __attribute__((ext_vector_type(8)));

#define DEV static __device__ __forceinline__

DEV u16 f2b(float f){
  u32 u = __builtin_bit_cast(u32, f);
  return (u16)((u + 0x7fffu + ((u >> 16) & 1u)) >> 16);
}
DEV float b2f(u16 h){ u32 u = ((u32)h) << 16; return __builtin_bit_cast(float, u); }
DEV u32 pack2(float a, float b){ return (u32)f2b(a) | ((u32)f2b(b) << 16); }
DEV uint4 pack8(const float* f){
  uint4 r; r.x = pack2(f[0],f[1]); r.y = pack2(f[2],f[3]);
  r.z = pack2(f[4],f[5]); r.w = pack2(f[6],f[7]); return r;
}
DEV void unpack8(uint4 u, float* f){
  f[0]=b2f((u16)(u.x&0xffffu)); f[1]=b2f((u16)(u.x>>16));
  f[2]=b2f((u16)(u.y&0xffffu)); f[3]=b2f((u16)(u.y>>16));
  f[4]=b2f((u16)(u.z&0xffffu)); f[5]=b2f((u16)(u.z>>16));
  f[6]=b2f((u16)(u.w&0xffffu)); f[7]=b2f((u16)(u.w>>16));
}
// gelu-tanh via sigmoid identity: 0.5x(1+tanh(z)) = x*sigma(2z); hardware v_exp
DEV float gelu_t(float x){
  const float z2 = 1.5957691216057308f*(x + 0.044715f*x*x*x);
  return x / (1.f + __expf(-z2));
}
// async global->LDS, 16B per lane; LDS dest = wave-uniform base + lane*16
DEV void g2l16(const u16* g, u16* l){
  __builtin_amdgcn_global_load_lds(
    (const __attribute__((address_space(1))) u32*)g,
    (__attribute__((address_space(3))) u32*)l, 16, 0, 0);
}

// ---------------- LayerNorm: fp32 [rows][1024] -> bf16 ----------------
__global__ __launch_bounds__(256)
void ln_k(const float* __restrict__ x, const float* __restrict__ gamma,
          const float* __restrict__ beta, u16* __restrict__ out)
{
  const int row = blockIdx.x;
  const int t = threadIdx.x;
  const float4 v = ((const float4*)(x + (size_t)row*1024))[t];
  float s  = v.x+v.y+v.z+v.w;
  float ss = v.x*v.x+v.y*v.y+v.z*v.z+v.w*v.w;
  #pragma unroll
  for (int o=32;o;o>>=1){ s += __shfl_xor(s,o); ss += __shfl_xor(ss,o); }
  __shared__ float rs[4], rq[4];
  if ((t&63)==0){ rs[t>>6]=s; rq[t>>6]=ss; }
  __syncthreads();
  s  = rs[0]+rs[1]+rs[2]+rs[3];
  ss = rq[0]+rq[1]+rq[2]+rq[3];
  const float mean = s*(1.f/1024.f);
  const float var  = ss*(1.f/1024.f) - mean*mean;
  const float inv  = rsqrtf(var + 1e-5f);
  const float4 g4 = ((const float4*)gamma)[t];
  const float4 b4 = ((const float4*)beta)[t];
  float o[4];
  o[0]=(v.x-mean)*inv*g4.x+b4.x; o[1]=(v.y-mean)*inv*g4.y+b4.y;
  o[2]=(v.z-mean)*inv*g4.z+b4.z; o[3]=(v.w-mean)*inv*g4.w+b4.w;
  uint2 w; w.x = pack2(o[0],o[1]); w.y = pack2(o[2],o[3]);
  *(uint2*)(out + (size_t)row*1024 + t*4) = w;
}

// ------------- weight conversion: W [K][N] fp32 -> WT [N][K] bf16 -------------
__global__ __launch_bounds__(256)
void wconv_k(const float* __restrict__ W, u16* __restrict__ WT, int K, int N)
{
  __shared__ float tile[32][33];
  const int k0 = blockIdx.y<<5, n0 = blockIdx.x<<5;
  const int tx = threadIdx.x & 31, ty = threadIdx.x >> 5;   // 32 x 8
  #pragma unroll
  for (int r=0;r<32;r+=8)
    tile[ty+r][tx] = W[(size_t)(k0+ty+r)*N + n0+tx];
  __syncthreads();
  #pragma unroll
  for (int r=0;r<32;r+=8)
    WT[(size_t)(n0+ty+r)*K + k0+tx] = f2b(tile[tx][ty+r]);
}

// ---- bf16 MFMA GEMM, 128x256 tile, BK=32, dbuf + early-issue + XOR swizzle ----
// (r13 structure: 3 blocks/CU; inter-block wave overlap hides the barrier drain.)
#define EPI_QKV  0
#define EPI_WO   1
#define EPI_GELU 2
#define EPI_FF2  3   // out = res + acc + bias (res aliases out; single pass)

template<int EPI>
__global__ __launch_bounds__(512)
void gemm3_k(const u16* __restrict__ A, const u16* __restrict__ BT,
             int K, int lda, int ldb, int N,
             u16* __restrict__ obf, float* __restrict__ of32,
             const float* __restrict__ res, const float* __restrict__ bias)
{
  __shared__ __align__(16) u16 SA[2*4096];    // [buf][128 rows][32 k]
  __shared__ __align__(16) u16 SB[2*8192];    // [buf][256 rows][32 k]
  const int t = threadIdx.x, wid = t>>6, lane = t&63;
  const int c = lane&15, g = lane>>4;
  const int wm = wid>>2, wn = wid&3;
  const int nwg = gridDim.x*gridDim.y;
  const int lb = blockIdx.y*gridDim.x + blockIdx.x;
  const int nl = (lb&7)*(nwg>>3) + (lb>>3);
  const int bx = nl % gridDim.x, by = nl / gridDim.x;
  const int m0 = by<<7, n0 = bx<<8;
  const int srow = lane>>2;
  const int scol = (lane&3)<<3;
  const int sxor = (srow&3)<<3;
  const int rowA = (wid<<4) + srow;
  const u16* aSrc  = A  + (size_t)(m0 + rowA)*lda + (scol ^ sxor);
  const u16* bSrc0 = BT + (size_t)(n0 + rowA)*ldb + (scol ^ sxor);
  const u16* bSrc1 = BT + (size_t)(n0 + 128 + rowA)*ldb + (scol ^ sxor);
  const int kx = (g<<3) ^ ((c&3)<<3);

  f32x4 acc[4][4];
  const f32x4 zz = {0.f,0.f,0.f,0.f};
  #pragma unroll
  for (int i=0;i<4;i++){ acc[i][0]=zz; acc[i][1]=zz; acc[i][2]=zz; acc[i][3]=zz; }

  g2l16(aSrc,  &SA[wid<<9]);
  g2l16(bSrc0, &SB[wid<<9]);
  g2l16(bSrc1, &SB[(wid<<9) + 4096]);
  __syncthreads();

  const int nt = K >> 5;
  for (int tt = 0; tt < nt; ++tt){
    const int cur = tt & 1;
    if (tt + 1 < nt){
      const int ko = (tt+1) << 5;
      g2l16(aSrc + ko,  &SA[((cur^1)<<12) + (wid<<9)]);
      g2l16(bSrc0 + ko, &SB[((cur^1)<<13) + (wid<<9)]);
      g2l16(bSrc1 + ko, &SB[((cur^1)<<13) + (wid<<9) + 4096]);
    }
    bf16x8 af[4], bf[4];
    #pragma unroll
    for (int i=0;i<4;i++)
      af[i] = *(const bf16x8*)&SA[(cur<<12) + ((wm<<6)+(i<<4)+c)*32 + kx];
    #pragma unroll
    for (int j=0;j<4;j++)
      bf[j] = *(const bf16x8*)&SB[(cur<<13) + ((wn<<6)+(j<<4)+c)*32 + kx];
    #pragma unroll
    for (int i=0;i<4;i++)
      #pragma unroll
      for (int j=0;j<4;j++)
        acc[i][j] = __builtin_amdgcn_mfma_f32_16x16x32_bf16(af[i], bf[j], acc[i][j], 0,0,0);
    __syncthreads();
  }

  #pragma unroll
  for (int i=0;i<4;i++){
    const int gr0 = m0 + (wm<<6) + (i<<4) + (g<<2);
    #pragma unroll
    for (int j=0;j<4;j++){
      const int gc = n0 + (wn<<6) + (j<<4) + c;
      #pragma unroll
      for (int r=0;r<4;r++){
        const int gr = gr0 + r;
        const float vv = acc[i][j][r];
        if (EPI==EPI_QKV){
          obf[((size_t)(gc>>10)<<24) + (size_t)gr*1024 + (gc&1023)] = f2b(vv);
        } else if (EPI==EPI_WO){
          const size_t idx = (size_t)gr*N + gc;
          of32[idx] = res[idx] + vv;
        } else if (EPI==EPI_GELU){
          obf[(size_t)gr*N + gc] = f2b(gelu_t(vv + bias[gc]));
        } else {
          const size_t idx = (size_t)gr*N + gc;
          of32[idx] = res[idx] + vv + bias[gc];   // residual + FF, single pass
        }
      }
    }
  }
}

// ------- per-segment memory contribution (MFMA): Mseg = elu(K)^T V, zseg -------
__global__ __launch_bounds__(256)
void memseg_k(const u16* __restrict__ kb, const u16* __restrict__ vb,
              float* __restrict__ Mseg, float* __restrict__ zseg)
{
  const int bid = blockIdx.x;           // b*64 + h*8 + seg
  const int seg = bid & 7, h = (bid>>3)&7, b = bid>>6;
  __shared__ __align__(16) u16 Kt[128*64];   // [dk][s] swizzled
  __shared__ __align__(16) u16 Vt[128*64];   // [dv][s] swizzled
  const int t=threadIdx.x, w=t>>6, lane=t&63, c=lane&15, g=lane>>4;

  f32x4 acc[2][8];
  f32x4 zacc[2];
  const f32x4 zzero = {0.f,0.f,0.f,0.f};
  #pragma unroll
  for (int d=0;d<2;d++){ zacc[d]=zzero;
    #pragma unroll
    for (int j=0;j<8;j++) acc[d][j]=zzero; }
  bf16x8 bones;
  { u16 tmp[8];
    #pragma unroll
    for (int e=0;e<8;e++) tmp[e] = (c==0) ? (u16)0x3F80 : (u16)0;
    bones = __builtin_bit_cast(bf16x8, *(uint4*)tmp); }

  for (int s0=0; s0<512; s0+=64){
    __syncthreads();
    {
      const int s = lane, dk0 = w<<5;
      const size_t grow = ((size_t)b*4096 + seg*512 + s0 + s)*1024 + h*128 + dk0;
      #pragma unroll
      for (int jj=0;jj<4;jj++){
        float kf[8], vf[8];
        unpack8(*(const uint4*)(kb + grow + jj*8), kf);
        unpack8(*(const uint4*)(vb + grow + jj*8), vf);
        #pragma unroll
        for (int e=0;e<8;e++){
          const int dk = dk0 + jj*8 + e;
          const float ek = kf[e]>0.f ? kf[e]+1.f : __expf(kf[e]);   // elu+1
          Kt[(dk<<6) + (s ^ ((dk&7)<<3))] = f2b(ek);
          Vt[(dk<<6) + (s ^ ((dk&7)<<3))] = f2b(vf[e]);
        }
      }
    }
    __syncthreads();
    #pragma unroll
    for (int ks=0;ks<2;ks++){
      const int kc = (ks<<5) + (g<<3);
      const bf16x8 a0 = *(const bf16x8*)&Kt[((((w<<1)  )*16 + c)<<6) + (kc ^ ((c&7)<<3))];
      const bf16x8 a1 = *(const bf16x8*)&Kt[((((w<<1)+1)*16 + c)<<6) + (kc ^ ((c&7)<<3))];
      zacc[0] = __builtin_amdgcn_mfma_f32_16x16x32_bf16(a0, bones, zacc[0], 0,0,0);
      zacc[1] = __builtin_amdgcn_mfma_f32_16x16x32_bf16(a1, bones, zacc[1], 0,0,0);
      #pragma unroll
      for (int j=0;j<8;j++){
        const bf16x8 bv = *(const bf16x8*)&Vt[(((j<<4) + c)<<6) + (kc ^ ((c&7)<<3))];
        acc[0][j] = __builtin_amdgcn_mfma_f32_16x16x32_bf16(a0, bv, acc[0][j], 0,0,0);
        acc[1][j] = __builtin_amdgcn_mfma_f32_16x16x32_bf16(a1, bv, acc[1][j], 0,0,0);
      }
    }
  }
  const size_t mb = (size_t)bid*16384;
  #pragma unroll
  for (int d=0;d<2;d++){
    const int dk = ((w<<1)+d)*16 + (g<<2);
    #pragma unroll
    for (int j=0;j<8;j++)
      #pragma unroll
      for (int r=0;r<4;r++)
        Mseg[mb + (size_t)(dk + r)*128 + (j<<4) + c] = acc[d][j][r];
    if (c==0){
      #pragma unroll
      for (int r=0;r<4;r++) zseg[(size_t)bid*128 + dk + r] = zacc[d][r];
    }
  }
}

// --- prefix scan over segments -> memBT (TRANSPOSED [dv][kd], bf16), zB ---
__global__ __launch_bounds__(256)
void scan_k(const float* __restrict__ Mseg, const float* __restrict__ zseg,
            u16* __restrict__ memBT, float* __restrict__ zB)
{
  const int bh = blockIdx.x >> 3, oct = blockIdx.x & 7;
  const int t = threadIdx.x;
  const int dv = (oct<<4) + (t&15);
  const int kd0 = (t>>4)<<3;
  float run[8];
  #pragma unroll
  for (int i=0;i<8;i++) run[i]=0.f;
  for (int seg=0; seg<8; seg++){
    const size_t base = ((size_t)bh*8 + seg)*16384;
    u16 tmp[8];
    #pragma unroll
    for (int i=0;i<8;i++) tmp[i] = f2b(run[i]);
    *(uint4*)(memBT + base + (size_t)dv*128 + kd0) = *(const uint4*)tmp;
    #pragma unroll
    for (int i=0;i<8;i++) run[i] += Mseg[base + (size_t)(kd0+i)*128 + dv];
  }
  if (oct==0 && t < 128){
    float zr = 1.f/128.f;
    for (int seg=0; seg<8; seg++){
      const size_t base = ((size_t)bh*8 + seg)*128;
      zB[base + t] = zr;
      zr += zseg[base + t];
    }
  }
}

// --- flash local attention (MFMA) + fused retrieval, low-pressure epilogue ---
__global__ __launch_bounds__(256,2)
void attn_k(const u16* __restrict__ qb, const u16* __restrict__ kb,
            const u16* __restrict__ vb, const u16* __restrict__ memBT,
            const float* __restrict__ zB, const float* __restrict__ betas,
            u16* __restrict__ attc)
{
  const int bid = blockIdx.x;
  const int s = bid & 255, rt = 7 - (bid >> 8);
  const int seg = s&7, h=(s>>3)&7, b=s>>6;
  __shared__ __align__(16) u16 smem[16384];  // Ks[0,8192)+Vt[8192,16384); epi: memT
  __shared__ __align__(16) u16 Ps[4096];     // P 64x64 swizzled; epi: z overlay
  u16* Ks = smem;
  u16* Vt = smem + 8192;
  float* zP = (float*)Ps;
  const int t=threadIdx.x, w=t>>6, lane=t&63, c=lane&15, g=lane>>4;
  const size_t base = ((size_t)b*4096 + seg*512)*1024 + h*128;

  bf16x8 af[4];
  {
    const u16* qsrc = qb + base + (size_t)(rt*64 + (w<<4) + c)*1024 + (g<<3);
    #pragma unroll
    for (int ks=0;ks<4;ks++) af[ks] = *(const bf16x8*)(qsrc + ks*32);
  }
  f32x4 acc[8];
  #pragma unroll
  for (int f=0;f<8;f++) acc[f] = (f32x4){0.f,0.f,0.f,0.f};
  float m_run[4], l_run[4];
  #pragma unroll
  for (int r=0;r<4;r++){ m_run[r] = -1e30f; l_run[r] = 0.f; }
  const float scl = 0.08838834764831845f;

  for (int kc=0; kc<=rt; kc++){
    __syncthreads();
    #pragma unroll
    for (int j=0;j<4;j++){
      const int row = (j<<2) + (lane>>4);
      const u16* src = kb + base + (size_t)(kc*64 + (w<<4) + row)*1024
                       + ((size_t)((lane&15) ^ (((w<<4)+row)&7)) << 3);
      g2l16(src, Ks + (((w<<4)+(j<<2))<<7));
    }
    {
      const int kr = lane, d0 = w<<5;
      const u16* vsrc = vb + base + (size_t)(kc*64+kr)*1024 + d0;
      #pragma unroll
      for (int jj=0;jj<4;jj++){
        const uint4 vv = *(const uint4*)(vsrc + jj*8);
        u16 tmp[8]; *(uint4*)tmp = vv;
        #pragma unroll
        for (int e=0;e<8;e++){
          const int dv = d0 + jj*8 + e;
          Vt[(dv<<6) + (kr ^ ((dv&7)<<3))] = tmp[e];
        }
      }
    }
    __syncthreads();
    f32x4 sv[4];
    #pragma unroll
    for (int j=0;j<4;j++) sv[j] = (f32x4){0.f,0.f,0.f,0.f};
    #pragma unroll
    for (int ks=0;ks<4;ks++)
      #pragma unroll
      for (int j=0;j<4;j++){
        const bf16x8 bk = *(const bf16x8*)&Ks[(((j<<4)+c)<<7) + ((((ks<<2)|g) ^ (c&7))<<3)];
        sv[j] = __builtin_amdgcn_mfma_f32_16x16x32_bf16(af[ks], bk, sv[j], 0,0,0);
      }
    const bool diag = (kc==rt);
    float p[4][4], rm[4], rsum[4];
    #pragma unroll
    for (int r=0;r<4;r++){
      float mx = -1e30f;
      #pragma unroll
      for (int j=0;j<4;j++){
        float svv = sv[j][r]*scl;
        if (diag && ((j<<4)+c) > ((w<<4) + (g<<2) + r)) svv = -1e30f;
        p[j][r] = svv;
        mx = fmaxf(mx, svv);
      }
      rm[r] = mx;
    }
    #pragma unroll
    for (int o=1;o<16;o<<=1)
      #pragma unroll
      for (int r=0;r<4;r++) rm[r] = fmaxf(rm[r], __shfl_xor(rm[r], o));
    #pragma unroll
    for (int r=0;r<4;r++){
      const float mn = fmaxf(m_run[r], rm[r]);
      const float sc = __expf(m_run[r] - mn);
      m_run[r] = mn;
      float sum = 0.f;
      #pragma unroll
      for (int j=0;j<4;j++){ p[j][r] = __expf(p[j][r]-mn); sum += p[j][r]; }
      rsum[r] = sum;
      l_run[r] *= sc;
      #pragma unroll
      for (int f=0;f<8;f++) acc[f][r] *= sc;
    }
    #pragma unroll
    for (int o=1;o<16;o<<=1)
      #pragma unroll
      for (int r=0;r<4;r++) rsum[r] += __shfl_xor(rsum[r], o);
    #pragma unroll
    for (int r=0;r<4;r++) l_run[r] += rsum[r];
    #pragma unroll
    for (int j=0;j<4;j++)
      #pragma unroll
      for (int r=0;r<4;r++){
        const int prow = (w<<4)+(g<<2)+r;
        Ps[(prow<<6) + (((j<<4)+c) ^ ((prow&7)<<3))] = f2b(p[j][r]);
      }
    #pragma unroll
    for (int ks2=0; ks2<2; ks2++){
      const bf16x8 pa = *(const bf16x8*)&Ps[(((w<<4)+c)<<6) + ((((ks2<<2)|g) ^ (c&7))<<3)];
      #pragma unroll
      for (int f=0;f<8;f++){
        const int dv = (f<<4)+c;
        const bf16x8 bv = *(const bf16x8*)&Vt[(dv<<6) + ((((ks2<<2)|g) ^ (c&7))<<3)];
        acc[f] = __builtin_amdgcn_mfma_f32_16x16x32_bf16(pa, bv, acc[f], 0,0,0);
      }
    }
  }
  // ---- epilogue: memT+z stage ----
  __syncthreads();
  {
    const size_t mbase = (((size_t)b*8+h)*8+seg) << 14;
    #pragma unroll
    for (int i=0;i<8;i++){
      const int row = (i<<2) + (lane>>4);
      const u16* src = memBT + mbase + ((size_t)((w<<5)+row)<<7)
                       + ((size_t)((lane&15) ^ (((w<<5)+row)&7)) << 3);
      g2l16(src, smem + (((w<<5)+(i<<2))<<7));
    }
    if (t < 128) zP[t] = zB[((((size_t)b*8+h)*8+seg)<<7) + t];
  }
  __syncthreads();
  // elu(Q)+1 in place (af -> sq fragments) + fp32 z-dot partial
  float dpart = 0.f;
  #pragma unroll
  for (int ks=0;ks<4;ks++){
    float f[8]; unpack8(__builtin_bit_cast(uint4, af[ks]), f);
    #pragma unroll
    for (int e=0;e<8;e++){
      f[e] = f[e]>0.f ? f[e]+1.f : __expf(f[e]);
      dpart += f[e] * zP[ks*32 + (g<<3) + e];
    }
    af[ks] = __builtin_bit_cast(bf16x8, pack8(f));
  }
  dpart += __shfl_xor(dpart, 16);
  dpart += __shfl_xor(dpart, 32);        // = den of q-row (w*16+c), all g
  float den[4];
  #pragma unroll
  for (int r=0;r<4;r++) den[r] = 1.f / __shfl(dpart, (g<<2)+r);
  // retrieval folded per-f + gated combine + direct stores
  #pragma unroll 2
  for (int f=0;f<8;f++){
    f32x4 nf = {0.f,0.f,0.f,0.f};
    #pragma unroll
    for (int ks=0;ks<4;ks++){
      const bf16x8 bm = *(const bf16x8*)&smem[(((f<<4)+c)<<7) + ((((ks<<2)|g) ^ (c&7))<<3)];
      nf = __builtin_amdgcn_mfma_f32_16x16x32_bf16(af[ks], bm, nf, 0,0,0);
    }
    const float bv = betas[(h<<7) + (f<<4) + c];
    const float gate = 1.f/(1.f+__expf(-bv));
    #pragma unroll
    for (int r=0;r<4;r++){
      const size_t idx = base + (size_t)(rt*64 + (w<<4) + (g<<2) + r)*1024 + (f<<4) + c;
      const float att = acc[f][r] / l_run[r];
      const float am  = nf[r] * den[r];
      attc[idx] = f2b(gate*am + (1.f-gate)*att);
    }
  }
}

extern "C" void kernel_launch(void* const* d_in, const int* in_sizes, int n_in,
                              void* d_out, int out_size, void* d_ws, size_t ws_size,
                              hipStream_t stream)
{
  (void)in_sizes; (void)n_in; (void)out_size; (void)ws_size;
  const float* x    = (const float*)d_in[0];
  const float* ln_g = (const float*)d_in[1];
  const float* ln_b = (const float*)d_in[2];
  const float* Wq   = (const float*)d_in[3];
  const float* Wk   = (const float*)d_in[4];
  const float* Wv   = (const float*)d_in[5];
  const float* Wo   = (const float*)d_in[6];
  const float* betas= (const float*)d_in[7];
  const float* w1   = (const float*)d_in[8];
  const float* b1   = (const float*)d_in[9];
  const float* w2   = (const float*)d_in[10];
  const float* b2   = (const float*)d_in[11];
  float* out = (float*)d_out;

  // ---- workspace: 96 MB qkv + 24 MB bf16 weights = 120 MB ----
  char* ws = (char*)d_ws;
  const size_t MB = 1048576;
  u16* qb  = (u16*)(ws);              // qb -> at (in-place) -> FF hidden (w/ kb)
  u16* kb  = (u16*)(ws + 32*MB);      // kb -> FF hidden (second half)
  u16* vb  = (u16*)(ws + 64*MB);      // vb -> h2 (LN2 out)
  u16* Wqkv= (u16*)(ws + 96*MB);      // [3072][1024] bf16 (Wq|Wk|Wv rows)
  u16* Wob = (u16*)(ws + 102*MB);
  u16* w1b = (u16*)(ws + 104*MB);     // [4096][1024], 8 MB
  u16* w2b = (u16*)(ws + 112*MB);     // [1024][4096], 8 MB
  // ---- d_out doubles as scratch before the Wo GEMM overwrites it ----
  char* ob = (char*)d_out;
  u16*   h    = (u16*)ob;             // 32 MB bf16 (LN1 out; dead after QKV)
  float* Mseg = (float*)(ob + 32*MB); // 16 MB
  u16*   memBT= (u16*)  (ob + 48*MB); // 8 MB
  float* zseg = (float*)(ob + 56*MB); // 128 KB
  float* zB   = (float*)(ob + 56*MB + 131072);
  u16*   at   = qb;
  u16*   h2   = vb;                   // LN2 out lives in vb (free after attn)
  u16*   gb2  = qb;                   // FF hidden chunk [8192][4096] = 64 MB (qb+kb)

  // weight conversion (fp32 [K][N] -> bf16 [N][K])
  wconv_k<<<dim3(32,32),256,0,stream>>>(Wq, Wqkv,              1024,1024);
  wconv_k<<<dim3(32,32),256,0,stream>>>(Wk, Wqkv+1024*1024,    1024,1024);
  wconv_k<<<dim3(32,32),256,0,stream>>>(Wv, Wqkv+2*1024*1024,  1024,1024);
  wconv_k<<<dim3(32,32),256,0,stream>>>(Wo, Wob, 1024,1024);
  wconv_k<<<dim3(128,32),256,0,stream>>>(w1, w1b, 1024,4096);
  wconv_k<<<dim3(32,128),256,0,stream>>>(w2, w2b, 4096,1024);

  ln_k<<<16384,256,0,stream>>>(x, ln_g, ln_b, h);
  // fused QKV: [16384,1024] x [1024,3072] -> qb|kb|vb
  gemm3_k<EPI_QKV><<<dim3(12,128),512,0,stream>>>(h, Wqkv, 1024,1024,1024, 3072,
                                                  qb, nullptr, nullptr, nullptr);
  memseg_k<<<256,256,0,stream>>>(kb, vb, Mseg, zseg);
  scan_k<<<256,256,0,stream>>>(Mseg, zseg, memBT, zB);
  attn_k<<<2048,256,0,stream>>>(qb, kb, vb, memBT, zB, betas, at);
  gemm3_k<EPI_WO><<<dim3(4,128),512,0,stream>>>(at, Wob, 1024,1024,1024, 1024,
                                                nullptr, out, x, nullptr);
  ln_k<<<16384,256,0,stream>>>(out, ln_g, ln_b, h2);
  // FF chunked over M (rows): 2 chunks of 8192 rows; hidden [8192][4096] bf16
  // fits qb+kb (64 MB). FF2 does full K=4096 in one pass: out = out + FF + b2.
  for (int mc = 0; mc < 2; mc++){
    const u16* hA = h2 + (size_t)mc*8192*1024;
    float*     oC = out + (size_t)mc*8192*1024;
    gemm3_k<EPI_GELU><<<dim3(16,64),512,0,stream>>>(hA, w1b, 1024,1024,1024, 4096,
                                                    gb2, nullptr, nullptr, b1);
    gemm3_k<EPI_FF2><<<dim3(4,64),512,0,stream>>>(gb2, w2b, 4096,4096,4096, 1024,
                                                  nullptr, oC, oC, b2);
  }
}

// Round 18
// 690.284 us; speedup vs baseline: 1.1363x; 1.0521x over previous
//
#include <hip/hip_runtime.h>

typedef unsigned short u16;
typedef unsigned int   u32;
typedef float f32x4 __attribute__((ext_vector_type(4)));
typedef short bf16x8 __attribute__((ext_vector_type(8)));

#define DEV static __device__ __forceinline__

DEV u16 f2b(float f){
  u32 u = __builtin_bit_cast(u32, f);
  return (u16)((u + 0x7fffu + ((u >> 16) & 1u)) >> 16);
}
DEV float b2f(u16 h){ u32 u = ((u32)h) << 16; return __builtin_bit_cast(float, u); }
DEV u32 pack2(float a, float b){ return (u32)f2b(a) | ((u32)f2b(b) << 16); }
DEV uint4 pack8(const float* f){
  uint4 r; r.x = pack2(f[0],f[1]); r.y = pack2(f[2],f[3]);
  r.z = pack2(f[4],f[5]); r.w = pack2(f[6],f[7]); return r;
}
DEV void unpack8(uint4 u, float* f){
  f[0]=b2f((u16)(u.x&0xffffu)); f[1]=b2f((u16)(u.x>>16));
  f[2]=b2f((u16)(u.y&0xffffu)); f[3]=b2f((u16)(u.y>>16));
  f[4]=b2f((u16)(u.z&0xffffu)); f[5]=b2f((u16)(u.z>>16));
  f[6]=b2f((u16)(u.w&0xffffu)); f[7]=b2f((u16)(u.w>>16));
}
// gelu-tanh via sigmoid identity: 0.5x(1+tanh(z)) = x*sigma(2z); hardware v_exp
DEV float gelu_t(float x){
  const float z2 = 1.5957691216057308f*(x + 0.044715f*x*x*x);
  return x / (1.f + __expf(-z2));
}
// async global->LDS, 16B per lane; LDS dest = wave-uniform base + lane*16
DEV void g2l16(const u16* g, u16* l){
  __builtin_amdgcn_global_load_lds(
    (const __attribute__((address_space(1))) u32*)g,
    (__attribute__((address_space(3))) u32*)l, 16, 0, 0);
}

// ---------------- LayerNorm: fp32 [rows][1024] -> bf16 ----------------
__global__ __launch_bounds__(256)
void ln_k(const float* __restrict__ x, const float* __restrict__ gamma,
          const float* __restrict__ beta, u16* __restrict__ out)
{
  const int row = blockIdx.x;
  const int t = threadIdx.x;
  const float4 v = ((const float4*)(x + (size_t)row*1024))[t];
  float s  = v.x+v.y+v.z+v.w;
  float ss = v.x*v.x+v.y*v.y+v.z*v.z+v.w*v.w;
  #pragma unroll
  for (int o=32;o;o>>=1){ s += __shfl_xor(s,o); ss += __shfl_xor(ss,o); }
  __shared__ float rs[4], rq[4];
  if ((t&63)==0){ rs[t>>6]=s; rq[t>>6]=ss; }
  __syncthreads();
  s  = rs[0]+rs[1]+rs[2]+rs[3];
  ss = rq[0]+rq[1]+rq[2]+rq[3];
  const float mean = s*(1.f/1024.f);
  const float var  = ss*(1.f/1024.f) - mean*mean;
  const float inv  = rsqrtf(var + 1e-5f);
  const float4 g4 = ((const float4*)gamma)[t];
  const float4 b4 = ((const float4*)beta)[t];
  float o[4];
  o[0]=(v.x-mean)*inv*g4.x+b4.x; o[1]=(v.y-mean)*inv*g4.y+b4.y;
  o[2]=(v.z-mean)*inv*g4.z+b4.z; o[3]=(v.w-mean)*inv*g4.w+b4.w;
  uint2 w; w.x = pack2(o[0],o[1]); w.y = pack2(o[2],o[3]);
  *(uint2*)(out + (size_t)row*1024 + t*4) = w;
}

// ------------- weight conversion: W [K][N] fp32 -> WT [N][K] bf16 -------------
__global__ __launch_bounds__(256)
void wconv_k(const float* __restrict__ W, u16* __restrict__ WT, int K, int N)
{
  __shared__ float tile[32][33];
  const int k0 = blockIdx.y<<5, n0 = blockIdx.x<<5;
  const int tx = threadIdx.x & 31, ty = threadIdx.x >> 5;   // 32 x 8
  #pragma unroll
  for (int r=0;r<32;r+=8)
    tile[ty+r][tx] = W[(size_t)(k0+ty+r)*N + n0+tx];
  __syncthreads();
  #pragma unroll
  for (int r=0;r<32;r+=8)
    WT[(size_t)(n0+ty+r)*K + k0+tx] = f2b(tile[tx][ty+r]);
}

// ---- bf16 MFMA GEMM, 128x256 tile, BK=32, dbuf + early-issue + XOR swizzle ----
// (r13 structure: 3 blocks/CU; inter-block wave overlap hides the barrier drain.)
#define EPI_QKV  0
#define EPI_WO   1
#define EPI_GELU 2
#define EPI_FF2  3   // out = out + acc + bias(chunk0 only) : RMW accumulate

template<int EPI>
__global__ __launch_bounds__(512)
void gemm3_k(const u16* __restrict__ A, const u16* __restrict__ BT,
             int K, int lda, int ldb, int N,
             u16* __restrict__ obf, float* __restrict__ of32,
             const float* __restrict__ res, const float* __restrict__ bias)
{
  __shared__ __align__(16) u16 SA[2*4096];    // [buf][128 rows][32 k]
  __shared__ __align__(16) u16 SB[2*8192];    // [buf][256 rows][32 k]
  const int t = threadIdx.x, wid = t>>6, lane = t&63;
  const int c = lane&15, g = lane>>4;
  const int wm = wid>>2, wn = wid&3;
  const int nwg = gridDim.x*gridDim.y;
  const int lb = blockIdx.y*gridDim.x + blockIdx.x;
  const int nl = (lb&7)*(nwg>>3) + (lb>>3);
  const int bx = nl % gridDim.x, by = nl / gridDim.x;
  const int m0 = by<<7, n0 = bx<<8;
  const int srow = lane>>2;
  const int scol = (lane&3)<<3;
  const int sxor = (srow&3)<<3;
  const int rowA = (wid<<4) + srow;
  const u16* aSrc  = A  + (size_t)(m0 + rowA)*lda + (scol ^ sxor);
  const u16* bSrc0 = BT + (size_t)(n0 + rowA)*ldb + (scol ^ sxor);
  const u16* bSrc1 = BT + (size_t)(n0 + 128 + rowA)*ldb + (scol ^ sxor);
  const int kx = (g<<3) ^ ((c&3)<<3);

  f32x4 acc[4][4];
  const f32x4 zz = {0.f,0.f,0.f,0.f};
  #pragma unroll
  for (int i=0;i<4;i++){ acc[i][0]=zz; acc[i][1]=zz; acc[i][2]=zz; acc[i][3]=zz; }

  g2l16(aSrc,  &SA[wid<<9]);
  g2l16(bSrc0, &SB[wid<<9]);
  g2l16(bSrc1, &SB[(wid<<9) + 4096]);
  __syncthreads();

  const int nt = K >> 5;
  for (int tt = 0; tt < nt; ++tt){
    const int cur = tt & 1;
    if (tt + 1 < nt){
      const int ko = (tt+1) << 5;
      g2l16(aSrc + ko,  &SA[((cur^1)<<12) + (wid<<9)]);
      g2l16(bSrc0 + ko, &SB[((cur^1)<<13) + (wid<<9)]);
      g2l16(bSrc1 + ko, &SB[((cur^1)<<13) + (wid<<9) + 4096]);
    }
    bf16x8 af[4], bf[4];
    #pragma unroll
    for (int i=0;i<4;i++)
      af[i] = *(const bf16x8*)&SA[(cur<<12) + ((wm<<6)+(i<<4)+c)*32 + kx];
    #pragma unroll
    for (int j=0;j<4;j++)
      bf[j] = *(const bf16x8*)&SB[(cur<<13) + ((wn<<6)+(j<<4)+c)*32 + kx];
    #pragma unroll
    for (int i=0;i<4;i++)
      #pragma unroll
      for (int j=0;j<4;j++)
        acc[i][j] = __builtin_amdgcn_mfma_f32_16x16x32_bf16(af[i], bf[j], acc[i][j], 0,0,0);
    __syncthreads();
  }

  #pragma unroll
  for (int i=0;i<4;i++){
    const int gr0 = m0 + (wm<<6) + (i<<4) + (g<<2);
    #pragma unroll
    for (int j=0;j<4;j++){
      const int gc = n0 + (wn<<6) + (j<<4) + c;
      #pragma unroll
      for (int r=0;r<4;r++){
        const int gr = gr0 + r;
        const float vv = acc[i][j][r];
        if (EPI==EPI_QKV){
          obf[((size_t)(gc>>10)<<24) + (size_t)gr*1024 + (gc&1023)] = f2b(vv);
        } else if (EPI==EPI_WO){
          const size_t idx = (size_t)gr*N + gc;
          of32[idx] = res[idx] + vv;
        } else if (EPI==EPI_GELU){
          obf[(size_t)gr*N + gc] = f2b(gelu_t(vv + bias[gc]));
        } else {
          const size_t idx = (size_t)gr*N + gc;
          of32[idx] = of32[idx] + vv + (bias ? bias[gc] : 0.f);
        }
      }
    }
  }
}

// ------- per-segment memory contribution (MFMA): Mseg = elu(K)^T V, zseg -------
__global__ __launch_bounds__(256)
void memseg_k(const u16* __restrict__ kb, const u16* __restrict__ vb,
              float* __restrict__ Mseg, float* __restrict__ zseg)
{
  const int bid = blockIdx.x;           // b*64 + h*8 + seg
  const int seg = bid & 7, h = (bid>>3)&7, b = bid>>6;
  __shared__ __align__(16) u16 Kt[128*64];   // [dk][s] swizzled
  __shared__ __align__(16) u16 Vt[128*64];   // [dv][s] swizzled
  const int t=threadIdx.x, w=t>>6, lane=t&63, c=lane&15, g=lane>>4;

  f32x4 acc[2][8];
  f32x4 zacc[2];
  const f32x4 zzero = {0.f,0.f,0.f,0.f};
  #pragma unroll
  for (int d=0;d<2;d++){ zacc[d]=zzero;
    #pragma unroll
    for (int j=0;j<8;j++) acc[d][j]=zzero; }
  bf16x8 bones;
  { u16 tmp[8];
    #pragma unroll
    for (int e=0;e<8;e++) tmp[e] = (c==0) ? (u16)0x3F80 : (u16)0;
    bones = __builtin_bit_cast(bf16x8, *(uint4*)tmp); }

  for (int s0=0; s0<512; s0+=64){
    __syncthreads();
    {
      const int s = lane, dk0 = w<<5;
      const size_t grow = ((size_t)b*4096 + seg*512 + s0 + s)*1024 + h*128 + dk0;
      #pragma unroll
      for (int jj=0;jj<4;jj++){
        float kf[8], vf[8];
        unpack8(*(const uint4*)(kb + grow + jj*8), kf);
        unpack8(*(const uint4*)(vb + grow + jj*8), vf);
        #pragma unroll
        for (int e=0;e<8;e++){
          const int dk = dk0 + jj*8 + e;
          const float ek = kf[e]>0.f ? kf[e]+1.f : __expf(kf[e]);   // elu+1
          Kt[(dk<<6) + (s ^ ((dk&7)<<3))] = f2b(ek);
          Vt[(dk<<6) + (s ^ ((dk&7)<<3))] = f2b(vf[e]);
        }
      }
    }
    __syncthreads();
    #pragma unroll
    for (int ks=0;ks<2;ks++){
      const int kc = (ks<<5) + (g<<3);
      const bf16x8 a0 = *(const bf16x8*)&Kt[((((w<<1)  )*16 + c)<<6) + (kc ^ ((c&7)<<3))];
      const bf16x8 a1 = *(const bf16x8*)&Kt[((((w<<1)+1)*16 + c)<<6) + (kc ^ ((c&7)<<3))];
      zacc[0] = __builtin_amdgcn_mfma_f32_16x16x32_bf16(a0, bones, zacc[0], 0,0,0);
      zacc[1] = __builtin_amdgcn_mfma_f32_16x16x32_bf16(a1, bones, zacc[1], 0,0,0);
      #pragma unroll
      for (int j=0;j<8;j++){
        const bf16x8 bv = *(const bf16x8*)&Vt[(((j<<4) + c)<<6) + (kc ^ ((c&7)<<3))];
        acc[0][j] = __builtin_amdgcn_mfma_f32_16x16x32_bf16(a0, bv, acc[0][j], 0,0,0);
        acc[1][j] = __builtin_amdgcn_mfma_f32_16x16x32_bf16(a1, bv, acc[1][j], 0,0,0);
      }
    }
  }
  const size_t mb = (size_t)bid*16384;
  #pragma unroll
  for (int d=0;d<2;d++){
    const int dk = ((w<<1)+d)*16 + (g<<2);
    #pragma unroll
    for (int j=0;j<8;j++)
      #pragma unroll
      for (int r=0;r<4;r++)
        Mseg[mb + (size_t)(dk + r)*128 + (j<<4) + c] = acc[d][j][r];
    if (c==0){
      #pragma unroll
      for (int r=0;r<4;r++) zseg[(size_t)bid*128 + dk + r] = zacc[d][r];
    }
  }
}

// --- prefix scan over segments -> memBT (TRANSPOSED [dv][kd], bf16), zB ---
__global__ __launch_bounds__(256)
void scan_k(const float* __restrict__ Mseg, const float* __restrict__ zseg,
            u16* __restrict__ memBT, float* __restrict__ zB)
{
  const int bh = blockIdx.x >> 3, oct = blockIdx.x & 7;
  const int t = threadIdx.x;
  const int dv = (oct<<4) + (t&15);
  const int kd0 = (t>>4)<<3;
  float run[8];
  #pragma unroll
  for (int i=0;i<8;i++) run[i]=0.f;
  for (int seg=0; seg<8; seg++){
    const size_t base = ((size_t)bh*8 + seg)*16384;
    u16 tmp[8];
    #pragma unroll
    for (int i=0;i<8;i++) tmp[i] = f2b(run[i]);
    *(uint4*)(memBT + base + (size_t)dv*128 + kd0) = *(const uint4*)tmp;
    #pragma unroll
    for (int i=0;i<8;i++) run[i] += Mseg[base + (size_t)(kd0+i)*128 + dv];
  }
  if (oct==0 && t < 128){
    float zr = 1.f/128.f;
    for (int seg=0; seg<8; seg++){
      const size_t base = ((size_t)bh*8 + seg)*128;
      zB[base + t] = zr;
      zr += zseg[base + t];
    }
  }
}

// --- flash local attention (MFMA) + fused retrieval, low-pressure epilogue ---
__global__ __launch_bounds__(256,2)
void attn_k(const u16* __restrict__ qb, const u16* __restrict__ kb,
            const u16* __restrict__ vb, const u16* __restrict__ memBT,
            const float* __restrict__ zB, const float* __restrict__ betas,
            u16* __restrict__ attc)
{
  const int bid = blockIdx.x;
  const int s = bid & 255, rt = 7 - (bid >> 8);
  const int seg = s&7, h=(s>>3)&7, b=s>>6;
  __shared__ __align__(16) u16 smem[16384];  // Ks[0,8192)+Vt[8192,16384); epi: memT
  __shared__ __align__(16) u16 Ps[4096];     // P 64x64 swizzled; epi: z overlay
  u16* Ks = smem;
  u16* Vt = smem + 8192;
  float* zP = (float*)Ps;
  const int t=threadIdx.x, w=t>>6, lane=t&63, c=lane&15, g=lane>>4;
  const size_t base = ((size_t)b*4096 + seg*512)*1024 + h*128;

  bf16x8 af[4];
  {
    const u16* qsrc = qb + base + (size_t)(rt*64 + (w<<4) + c)*1024 + (g<<3);
    #pragma unroll
    for (int ks=0;ks<4;ks++) af[ks] = *(const bf16x8*)(qsrc + ks*32);
  }
  f32x4 acc[8];
  #pragma unroll
  for (int f=0;f<8;f++) acc[f] = (f32x4){0.f,0.f,0.f,0.f};
  float m_run[4], l_run[4];
  #pragma unroll
  for (int r=0;r<4;r++){ m_run[r] = -1e30f; l_run[r] = 0.f; }
  const float scl = 0.08838834764831845f;

  for (int kc=0; kc<=rt; kc++){
    __syncthreads();
    #pragma unroll
    for (int j=0;j<4;j++){
      const int row = (j<<2) + (lane>>4);
      const u16* src = kb + base + (size_t)(kc*64 + (w<<4) + row)*1024
                       + ((size_t)((lane&15) ^ (((w<<4)+row)&7)) << 3);
      g2l16(src, Ks + (((w<<4)+(j<<2))<<7));
    }
    {
      const int kr = lane, d0 = w<<5;
      const u16* vsrc = vb + base + (size_t)(kc*64+kr)*1024 + d0;
      #pragma unroll
      for (int jj=0;jj<4;jj++){
        const uint4 vv = *(const uint4*)(vsrc + jj*8);
        u16 tmp[8]; *(uint4*)tmp = vv;
        #pragma unroll
        for (int e=0;e<8;e++){
          const int dv = d0 + jj*8 + e;
          Vt[(dv<<6) + (kr ^ ((dv&7)<<3))] = tmp[e];
        }
      }
    }
    __syncthreads();
    f32x4 sv[4];
    #pragma unroll
    for (int j=0;j<4;j++) sv[j] = (f32x4){0.f,0.f,0.f,0.f};
    #pragma unroll
    for (int ks=0;ks<4;ks++)
      #pragma unroll
      for (int j=0;j<4;j++){
        const bf16x8 bk = *(const bf16x8*)&Ks[(((j<<4)+c)<<7) + ((((ks<<2)|g) ^ (c&7))<<3)];
        sv[j] = __builtin_amdgcn_mfma_f32_16x16x32_bf16(af[ks], bk, sv[j], 0,0,0);
      }
    const bool diag = (kc==rt);
    float p[4][4], rm[4], rsum[4];
    #pragma unroll
    for (int r=0;r<4;r++){
      float mx = -1e30f;
      #pragma unroll
      for (int j=0;j<4;j++){
        float svv = sv[j][r]*scl;
        if (diag && ((j<<4)+c) > ((w<<4) + (g<<2) + r)) svv = -1e30f;
        p[j][r] = svv;
        mx = fmaxf(mx, svv);
      }
      rm[r] = mx;
    }
    #pragma unroll
    for (int o=1;o<16;o<<=1)
      #pragma unroll
      for (int r=0;r<4;r++) rm[r] = fmaxf(rm[r], __shfl_xor(rm[r], o));
    #pragma unroll
    for (int r=0;r<4;r++){
      const float mn = fmaxf(m_run[r], rm[r]);
      const float sc = __expf(m_run[r] - mn);
      m_run[r] = mn;
      float sum = 0.f;
      #pragma unroll
      for (int j=0;j<4;j++){ p[j][r] = __expf(p[j][r]-mn); sum += p[j][r]; }
      rsum[r] = sum;
      l_run[r] *= sc;
      #pragma unroll
      for (int f=0;f<8;f++) acc[f][r] *= sc;
    }
    #pragma unroll
    for (int o=1;o<16;o<<=1)
      #pragma unroll
      for (int r=0;r<4;r++) rsum[r] += __shfl_xor(rsum[r], o);
    #pragma unroll
    for (int r=0;r<4;r++) l_run[r] += rsum[r];
    #pragma unroll
    for (int j=0;j<4;j++)
      #pragma unroll
      for (int r=0;r<4;r++){
        const int prow = (w<<4)+(g<<2)+r;
        Ps[(prow<<6) + (((j<<4)+c) ^ ((prow&7)<<3))] = f2b(p[j][r]);
      }
    #pragma unroll
    for (int ks2=0; ks2<2; ks2++){
      const bf16x8 pa = *(const bf16x8*)&Ps[(((w<<4)+c)<<6) + ((((ks2<<2)|g) ^ (c&7))<<3)];
      #pragma unroll
      for (int f=0;f<8;f++){
        const int dv = (f<<4)+c;
        const bf16x8 bv = *(const bf16x8*)&Vt[(dv<<6) + ((((ks2<<2)|g) ^ (c&7))<<3)];
        acc[f] = __builtin_amdgcn_mfma_f32_16x16x32_bf16(pa, bv, acc[f], 0,0,0);
      }
    }
  }
  // ---- epilogue: memT+z stage ----
  __syncthreads();
  {
    const size_t mbase = (((size_t)b*8+h)*8+seg) << 14;
    #pragma unroll
    for (int i=0;i<8;i++){
      const int row = (i<<2) + (lane>>4);
      const u16* src = memBT + mbase + ((size_t)((w<<5)+row)<<7)
                       + ((size_t)((lane&15) ^ (((w<<5)+row)&7)) << 3);
      g2l16(src, smem + (((w<<5)+(i<<2))<<7));
    }
    if (t < 128) zP[t] = zB[((((size_t)b*8+h)*8+seg)<<7) + t];
  }
  __syncthreads();
  // elu(Q)+1 in place (af -> sq fragments) + fp32 z-dot partial
  float dpart = 0.f;
  #pragma unroll
  for (int ks=0;ks<4;ks++){
    float f[8]; unpack8(__builtin_bit_cast(uint4, af[ks]), f);
    #pragma unroll
    for (int e=0;e<8;e++){
      f[e] = f[e]>0.f ? f[e]+1.f : __expf(f[e]);
      dpart += f[e] * zP[ks*32 + (g<<3) + e];
    }
    af[ks] = __builtin_bit_cast(bf16x8, pack8(f));
  }
  dpart += __shfl_xor(dpart, 16);
  dpart += __shfl_xor(dpart, 32);        // = den of q-row (w*16+c), all g
  float den[4];
  #pragma unroll
  for (int r=0;r<4;r++) den[r] = 1.f / __shfl(dpart, (g<<2)+r);
  // retrieval folded per-f + gated combine + direct stores
  #pragma unroll 2
  for (int f=0;f<8;f++){
    f32x4 nf = {0.f,0.f,0.f,0.f};
    #pragma unroll
    for (int ks=0;ks<4;ks++){
      const bf16x8 bm = *(const bf16x8*)&smem[(((f<<4)+c)<<7) + ((((ks<<2)|g) ^ (c&7))<<3)];
      nf = __builtin_amdgcn_mfma_f32_16x16x32_bf16(af[ks], bm, nf, 0,0,0);
    }
    const float bv = betas[(h<<7) + (f<<4) + c];
    const float gate = 1.f/(1.f+__expf(-bv));
    #pragma unroll
    for (int r=0;r<4;r++){
      const size_t idx = base + (size_t)(rt*64 + (w<<4) + (g<<2) + r)*1024 + (f<<4) + c;
      const float att = acc[f][r] / l_run[r];
      const float am  = nf[r] * den[r];
      attc[idx] = f2b(gate*am + (1.f-gate)*att);
    }
  }
}

extern "C" void kernel_launch(void* const* d_in, const int* in_sizes, int n_in,
                              void* d_out, int out_size, void* d_ws, size_t ws_size,
                              hipStream_t stream)
{
  (void)in_sizes; (void)n_in; (void)out_size; (void)ws_size;
  const float* x    = (const float*)d_in[0];
  const float* ln_g = (const float*)d_in[1];
  const float* ln_b = (const float*)d_in[2];
  const float* Wq   = (const float*)d_in[3];
  const float* Wk   = (const float*)d_in[4];
  const float* Wv   = (const float*)d_in[5];
  const float* Wo   = (const float*)d_in[6];
  const float* betas= (const float*)d_in[7];
  const float* w1   = (const float*)d_in[8];
  const float* b1   = (const float*)d_in[9];
  const float* w2   = (const float*)d_in[10];
  const float* b2   = (const float*)d_in[11];
  float* out = (float*)d_out;

  // ---- workspace: 96 MB qkv + 24 MB bf16 weights = 120 MB ----
  char* ws = (char*)d_ws;
  const size_t MB = 1048576;
  u16* qb  = (u16*)(ws);              // qb -> at (in-place) -> FF hidden (w/ kb)
  u16* kb  = (u16*)(ws + 32*MB);      // kb -> FF hidden (second half)
  u16* vb  = (u16*)(ws + 64*MB);      // vb -> h2 (LN2 out)
  u16* Wqkv= (u16*)(ws + 96*MB);      // [3072][1024] bf16 (Wq|Wk|Wv rows)
  u16* Wob = (u16*)(ws + 102*MB);
  u16* w1b = (u16*)(ws + 104*MB);     // [4096][1024], 8 MB
  u16* w2b = (u16*)(ws + 112*MB);     // [1024][4096], 8 MB
  // ---- d_out doubles as scratch before the Wo GEMM overwrites it ----
  char* ob = (char*)d_out;
  u16*   h    = (u16*)ob;             // 32 MB bf16 (LN1 out; dead after QKV)
  float* Mseg = (float*)(ob + 32*MB); // 16 MB
  u16*   memBT= (u16*)  (ob + 48*MB); // 8 MB
  float* zseg = (float*)(ob + 56*MB); // 128 KB
  float* zB   = (float*)(ob + 56*MB + 131072);
  u16*   at   = qb;
  u16*   h2   = vb;                   // LN2 out lives in vb (free after attn)
  u16*   gb2  = qb;                   // FF hidden chunk: 64 MB spanning qb+kb

  // weight conversion (fp32 [K][N] -> bf16 [N][K])
  wconv_k<<<dim3(32,32),256,0,stream>>>(Wq, Wqkv,              1024,1024);
  wconv_k<<<dim3(32,32),256,0,stream>>>(Wk, Wqkv+1024*1024,    1024,1024);
  wconv_k<<<dim3(32,32),256,0,stream>>>(Wv, Wqkv+2*1024*1024,  1024,1024);
  wconv_k<<<dim3(32,32),256,0,stream>>>(Wo, Wob, 1024,1024);
  wconv_k<<<dim3(128,32),256,0,stream>>>(w1, w1b, 1024,4096);
  wconv_k<<<dim3(32,128),256,0,stream>>>(w2, w2b, 4096,1024);

  ln_k<<<16384,256,0,stream>>>(x, ln_g, ln_b, h);
  // fused QKV: [16384,1024] x [1024,3072] -> qb|kb|vb
  gemm3_k<EPI_QKV><<<dim3(12,128),512,0,stream>>>(h, Wqkv, 1024,1024,1024, 3072,
                                                  qb, nullptr, nullptr, nullptr);
  memseg_k<<<256,256,0,stream>>>(kb, vb, Mseg, zseg);
  scan_k<<<256,256,0,stream>>>(Mseg, zseg, memBT, zB);
  attn_k<<<2048,256,0,stream>>>(qb, kb, vb, memBT, zB, betas, at);
  gemm3_k<EPI_WO><<<dim3(4,128),512,0,stream>>>(at, Wob, 1024,1024,1024, 1024,
                                                nullptr, out, x, nullptr);
  ln_k<<<16384,256,0,stream>>>(out, ln_g, ln_b, h2);
  // FF chunked over HIDDEN dim: 2 chunks of 2048 cols (hidden chunk = 64 MB in qb+kb)
  for (int cc = 0; cc < 2; cc++){
    gemm3_k<EPI_GELU><<<dim3(8,128),512,0,stream>>>(h2, w1b + (size_t)cc*2048*1024,
                                                    1024,1024,1024, 2048,
                                                    gb2, nullptr, nullptr, b1 + cc*2048);
    gemm3_k<EPI_FF2><<<dim3(4,128),512,0,stream>>>(gb2, w2b + (size_t)cc*2048,
                                                   2048,2048,4096, 1024,
                                                   nullptr, out, nullptr,
                                                   cc==0 ? b2 : nullptr);
  }
}

// Round 19
// 676.606 us; speedup vs baseline: 1.1593x; 1.0202x over previous
//
#include <hip/hip_runtime.h>

typedef unsigned short u16;
typedef unsigned int   u32;
typedef float f32x4 __attribute__((ext_vector_type(4)));
typedef short bf16x8 __attribute__((ext_vector_type(8)));

#define DEV static __device__ __forceinline__

DEV u16 f2b(float f){
  u32 u = __builtin_bit_cast(u32, f);
  return (u16)((u + 0x7fffu + ((u >> 16) & 1u)) >> 16);
}
DEV float b2f(u16 h){ u32 u = ((u32)h) << 16; return __builtin_bit_cast(float, u); }
DEV u32 pack2(float a, float b){ return (u32)f2b(a) | ((u32)f2b(b) << 16); }
DEV uint4 pack8(const float* f){
  uint4 r; r.x = pack2(f[0],f[1]); r.y = pack2(f[2],f[3]);
  r.z = pack2(f[4],f[5]); r.w = pack2(f[6],f[7]); return r;
}
DEV void unpack8(uint4 u, float* f){
  f[0]=b2f((u16)(u.x&0xffffu)); f[1]=b2f((u16)(u.x>>16));
  f[2]=b2f((u16)(u.y&0xffffu)); f[3]=b2f((u16)(u.y>>16));
  f[4]=b2f((u16)(u.z&0xffffu)); f[5]=b2f((u16)(u.z>>16));
  f[6]=b2f((u16)(u.w&0xffffu)); f[7]=b2f((u16)(u.w>>16));
}
// gelu-tanh via sigmoid identity: 0.5x(1+tanh(z)) = x*sigma(2z); hardware v_exp
DEV float gelu_t(float x){
  const float z2 = 1.5957691216057308f*(x + 0.044715f*x*x*x);
  return x / (1.f + __expf(-z2));
}
// async global->LDS, 16B per lane; LDS dest = wave-uniform base + lane*16
DEV void g2l16(const u16* g, u16* l){
  __builtin_amdgcn_global_load_lds(
    (const __attribute__((address_space(1))) u32*)g,
    (__attribute__((address_space(3))) u32*)l, 16, 0, 0);
}

// ---------------- LayerNorm: fp32 [rows][1024] -> bf16 ----------------
__global__ __launch_bounds__(256)
void ln_k(const float* __restrict__ x, const float* __restrict__ gamma,
          const float* __restrict__ beta, u16* __restrict__ out)
{
  const int row = blockIdx.x;
  const int t = threadIdx.x;
  const float4 v = ((const float4*)(x + (size_t)row*1024))[t];
  float s  = v.x+v.y+v.z+v.w;
  float ss = v.x*v.x+v.y*v.y+v.z*v.z+v.w*v.w;
  #pragma unroll
  for (int o=32;o;o>>=1){ s += __shfl_xor(s,o); ss += __shfl_xor(ss,o); }
  __shared__ float rs[4], rq[4];
  if ((t&63)==0){ rs[t>>6]=s; rq[t>>6]=ss; }
  __syncthreads();
  s  = rs[0]+rs[1]+rs[2]+rs[3];
  ss = rq[0]+rq[1]+rq[2]+rq[3];
  const float mean = s*(1.f/1024.f);
  const float var  = ss*(1.f/1024.f) - mean*mean;
  const float inv  = rsqrtf(var + 1e-5f);
  const float4 g4 = ((const float4*)gamma)[t];
  const float4 b4 = ((const float4*)beta)[t];
  float o[4];
  o[0]=(v.x-mean)*inv*g4.x+b4.x; o[1]=(v.y-mean)*inv*g4.y+b4.y;
  o[2]=(v.z-mean)*inv*g4.z+b4.z; o[3]=(v.w-mean)*inv*g4.w+b4.w;
  uint2 w; w.x = pack2(o[0],o[1]); w.y = pack2(o[2],o[3]);
  *(uint2*)(out + (size_t)row*1024 + t*4) = w;
}

// ------------- weight conversion: W [K][N] fp32 -> WT [N][K] bf16 -------------
__global__ __launch_bounds__(256)
void wconv_k(const float* __restrict__ W, u16* __restrict__ WT, int K, int N)
{
  __shared__ float tile[32][33];
  const int k0 = blockIdx.y<<5, n0 = blockIdx.x<<5;
  const int tx = threadIdx.x & 31, ty = threadIdx.x >> 5;   // 32 x 8
  #pragma unroll
  for (int r=0;r<32;r+=8)
    tile[ty+r][tx] = W[(size_t)(k0+ty+r)*N + n0+tx];
  __syncthreads();
  #pragma unroll
  for (int r=0;r<32;r+=8)
    WT[(size_t)(n0+ty+r)*K + k0+tx] = f2b(tile[tx][ty+r]);
}

// ---- bf16 MFMA GEMM, 128x256 tile, BK=32, dbuf + early-issue + XOR swizzle ----
#define EPI_QKV  0
#define EPI_WO   1
#define EPI_GELU 2
#define EPI_FF2  3   // out = out + acc + bias(chunk0 only) : RMW accumulate

template<int EPI>
__global__ __launch_bounds__(512)
void gemm3_k(const u16* __restrict__ A, const u16* __restrict__ BT,
             int K, int lda, int ldb, int N,
             u16* __restrict__ obf, float* __restrict__ of32,
             const float* __restrict__ res, const float* __restrict__ bias)
{
  __shared__ __align__(16) u16 SA[2*4096];    // [buf][128 rows][32 k]
  __shared__ __align__(16) u16 SB[2*8192];    // [buf][256 rows][32 k]
  const int t = threadIdx.x, wid = t>>6, lane = t&63;
  const int c = lane&15, g = lane>>4;
  const int wm = wid>>2, wn = wid&3;
  const int nwg = gridDim.x*gridDim.y;
  const int lb = blockIdx.y*gridDim.x + blockIdx.x;
  const int nl = (lb&7)*(nwg>>3) + (lb>>3);
  const int bx = nl % gridDim.x, by = nl / gridDim.x;
  const int m0 = by<<7, n0 = bx<<8;
  const int srow = lane>>2;
  const int scol = (lane&3)<<3;
  const int sxor = (srow&3)<<3;
  const int rowA = (wid<<4) + srow;
  const u16* aSrc  = A  + (size_t)(m0 + rowA)*lda + (scol ^ sxor);
  const u16* bSrc0 = BT + (size_t)(n0 + rowA)*ldb + (scol ^ sxor);
  const u16* bSrc1 = BT + (size_t)(n0 + 128 + rowA)*ldb + (scol ^ sxor);
  const int kx = (g<<3) ^ ((c&3)<<3);

  f32x4 acc[4][4];
  const f32x4 zz = {0.f,0.f,0.f,0.f};
  #pragma unroll
  for (int i=0;i<4;i++){ acc[i][0]=zz; acc[i][1]=zz; acc[i][2]=zz; acc[i][3]=zz; }

  g2l16(aSrc,  &SA[wid<<9]);
  g2l16(bSrc0, &SB[wid<<9]);
  g2l16(bSrc1, &SB[(wid<<9) + 4096]);
  __syncthreads();

  const int nt = K >> 5;
  for (int tt = 0; tt < nt; ++tt){
    const int cur = tt & 1;
    if (tt + 1 < nt){
      const int ko = (tt+1) << 5;
      g2l16(aSrc + ko,  &SA[((cur^1)<<12) + (wid<<9)]);
      g2l16(bSrc0 + ko, &SB[((cur^1)<<13) + (wid<<9)]);
      g2l16(bSrc1 + ko, &SB[((cur^1)<<13) + (wid<<9) + 4096]);
    }
    bf16x8 af[4], bf[4];
    #pragma unroll
    for (int i=0;i<4;i++)
      af[i] = *(const bf16x8*)&SA[(cur<<12) + ((wm<<6)+(i<<4)+c)*32 + kx];
    #pragma unroll
    for (int j=0;j<4;j++)
      bf[j] = *(const bf16x8*)&SB[(cur<<13) + ((wn<<6)+(j<<4)+c)*32 + kx];
    #pragma unroll
    for (int i=0;i<4;i++)
      #pragma unroll
      for (int j=0;j<4;j++)
        acc[i][j] = __builtin_amdgcn_mfma_f32_16x16x32_bf16(af[i], bf[j], acc[i][j], 0,0,0);
    __syncthreads();
  }

  #pragma unroll
  for (int i=0;i<4;i++){
    const int gr0 = m0 + (wm<<6) + (i<<4) + (g<<2);
    #pragma unroll
    for (int j=0;j<4;j++){
      const int gc = n0 + (wn<<6) + (j<<4) + c;
      #pragma unroll
      for (int r=0;r<4;r++){
        const int gr = gr0 + r;
        const float vv = acc[i][j][r];
        if (EPI==EPI_QKV){
          obf[((size_t)(gc>>10)<<24) + (size_t)gr*1024 + (gc&1023)] = f2b(vv);
        } else if (EPI==EPI_WO){
          const size_t idx = (size_t)gr*N + gc;
          of32[idx] = res[idx] + vv;
        } else if (EPI==EPI_GELU){
          obf[(size_t)gr*N + gc] = f2b(gelu_t(vv + bias[gc]));
        } else {
          const size_t idx = (size_t)gr*N + gc;
          of32[idx] = of32[idx] + vv + (bias ? bias[gc] : 0.f);
        }
      }
    }
  }
}

// ------- per-segment memory contribution (MFMA): Mseg = elu(K)^T V, zseg -------
__global__ __launch_bounds__(256)
void memseg_k(const u16* __restrict__ kb, const u16* __restrict__ vb,
              float* __restrict__ Mseg, float* __restrict__ zseg)
{
  const int bid = blockIdx.x;           // b*64 + h*8 + seg
  const int seg = bid & 7, h = (bid>>3)&7, b = bid>>6;
  __shared__ __align__(16) u16 Kt[128*64];   // [dk][s] swizzled
  __shared__ __align__(16) u16 Vt[128*64];   // [dv][s] swizzled
  const int t=threadIdx.x, w=t>>6, lane=t&63, c=lane&15, g=lane>>4;

  f32x4 acc[2][8];
  f32x4 zacc[2];
  const f32x4 zzero = {0.f,0.f,0.f,0.f};
  #pragma unroll
  for (int d=0;d<2;d++){ zacc[d]=zzero;
    #pragma unroll
    for (int j=0;j<8;j++) acc[d][j]=zzero; }
  bf16x8 bones;
  { u16 tmp[8];
    #pragma unroll
    for (int e=0;e<8;e++) tmp[e] = (c==0) ? (u16)0x3F80 : (u16)0;
    bones = __builtin_bit_cast(bf16x8, *(uint4*)tmp); }

  for (int s0=0; s0<512; s0+=64){
    __syncthreads();
    {
      const int s = lane, dk0 = w<<5;
      const size_t grow = ((size_t)b*4096 + seg*512 + s0 + s)*1024 + h*128 + dk0;
      #pragma unroll
      for (int jj=0;jj<4;jj++){
        float kf[8], vf[8];
        unpack8(*(const uint4*)(kb + grow + jj*8), kf);
        unpack8(*(const uint4*)(vb + grow + jj*8), vf);
        #pragma unroll
        for (int e=0;e<8;e++){
          const int dk = dk0 + jj*8 + e;
          const float ek = kf[e]>0.f ? kf[e]+1.f : __expf(kf[e]);   // elu+1
          Kt[(dk<<6) + (s ^ ((dk&7)<<3))] = f2b(ek);
          Vt[(dk<<6) + (s ^ ((dk&7)<<3))] = f2b(vf[e]);
        }
      }
    }
    __syncthreads();
    #pragma unroll
    for (int ks=0;ks<2;ks++){
      const int kc = (ks<<5) + (g<<3);
      const bf16x8 a0 = *(const bf16x8*)&Kt[((((w<<1)  )*16 + c)<<6) + (kc ^ ((c&7)<<3))];
      const bf16x8 a1 = *(const bf16x8*)&Kt[((((w<<1)+1)*16 + c)<<6) + (kc ^ ((c&7)<<3))];
      zacc[0] = __builtin_amdgcn_mfma_f32_16x16x32_bf16(a0, bones, zacc[0], 0,0,0);
      zacc[1] = __builtin_amdgcn_mfma_f32_16x16x32_bf16(a1, bones, zacc[1], 0,0,0);
      #pragma unroll
      for (int j=0;j<8;j++){
        const bf16x8 bv = *(const bf16x8*)&Vt[(((j<<4) + c)<<6) + (kc ^ ((c&7)<<3))];
        acc[0][j] = __builtin_amdgcn_mfma_f32_16x16x32_bf16(a0, bv, acc[0][j], 0,0,0);
        acc[1][j] = __builtin_amdgcn_mfma_f32_16x16x32_bf16(a1, bv, acc[1][j], 0,0,0);
      }
    }
  }
  const size_t mb = (size_t)bid*16384;
  #pragma unroll
  for (int d=0;d<2;d++){
    const int dk = ((w<<1)+d)*16 + (g<<2);
    #pragma unroll
    for (int j=0;j<8;j++)
      #pragma unroll
      for (int r=0;r<4;r++)
        Mseg[mb + (size_t)(dk + r)*128 + (j<<4) + c] = acc[d][j][r];
    if (c==0){
      #pragma unroll
      for (int r=0;r<4;r++) zseg[(size_t)bid*128 + dk + r] = zacc[d][r];
    }
  }
}

// --- prefix scan over segments -> memBT (TRANSPOSED [dv][kd], bf16), zB ---
__global__ __launch_bounds__(256)
void scan_k(const float* __restrict__ Mseg, const float* __restrict__ zseg,
            u16* __restrict__ memBT, float* __restrict__ zB)
{
  const int bh = blockIdx.x >> 3, oct = blockIdx.x & 7;
  const int t = threadIdx.x;
  const int dv = (oct<<4) + (t&15);
  const int kd0 = (t>>4)<<3;
  float run[8];
  #pragma unroll
  for (int i=0;i<8;i++) run[i]=0.f;
  for (int seg=0; seg<8; seg++){
    const size_t base = ((size_t)bh*8 + seg)*16384;
    u16 tmp[8];
    #pragma unroll
    for (int i=0;i<8;i++) tmp[i] = f2b(run[i]);
    *(uint4*)(memBT + base + (size_t)dv*128 + kd0) = *(const uint4*)tmp;
    #pragma unroll
    for (int i=0;i<8;i++) run[i] += Mseg[base + (size_t)(kd0+i)*128 + dv];
  }
  if (oct==0 && t < 128){
    float zr = 1.f/128.f;
    for (int seg=0; seg<8; seg++){
      const size_t base = ((size_t)bh*8 + seg)*128;
      zB[base + t] = zr;
      zr += zseg[base + t];
    }
  }
}

// --- flash local attention + fused retrieval, rt-PAIRED: 1024 blocks x 512 thr ---
// Block handles q-tiles {rt0=2p, rt1=2p+1} of one (b,h,seg): waves 0-3 own rt0,
// waves 4-7 own rt1. K/V/memT staged ONCE per block -> tile-reads 36->20 per
// (b,h,seg). Same primitives/barrier semantics; P stays wave-local. In-place
// safe (block reads/writes only its own 128 q-rows).
__global__ __launch_bounds__(512,2)
void attn_k(const u16* __restrict__ qb, const u16* __restrict__ kb,
            const u16* __restrict__ vb, const u16* __restrict__ memBT,
            const float* __restrict__ zB, const float* __restrict__ betas,
            u16* __restrict__ attc)
{
  const int bid = blockIdx.x;
  const int s = bid & 255;                 // (b,h,seg)
  const int pr = 3 - (bid >> 8);           // pair index, heavy first
  const int seg = s&7, h=(s>>3)&7, b=s>>6;
  __shared__ __align__(16) u16 smem[16384];  // Ks[0,8192)+Vt[8192,16384); epi: memT
  __shared__ __align__(16) u16 Ps[8192];     // P 128x64 (two 64-row halves); epi: z
  u16* Ks = smem;
  u16* Vt = smem + 8192;
  float* zP = (float*)Ps;
  const int t=threadIdx.x, w=t>>6, lane=t&63, c=lane&15, g=lane>>4;
  const int half = w>>2, wl = w&3;         // half: 0->rt0, 1->rt1
  const int myrt = (pr<<1) + half;
  const int rt1  = (pr<<1) + 1;
  const size_t base = ((size_t)b*4096 + seg*512)*1024 + h*128;

  bf16x8 af[4];
  {
    const u16* qsrc = qb + base + (size_t)(myrt*64 + (wl<<4) + c)*1024 + (g<<3);
    #pragma unroll
    for (int ks=0;ks<4;ks++) af[ks] = *(const bf16x8*)(qsrc + ks*32);
  }
  f32x4 acc[8];
  #pragma unroll
  for (int f=0;f<8;f++) acc[f] = (f32x4){0.f,0.f,0.f,0.f};
  float m_run[4], l_run[4];
  #pragma unroll
  for (int r=0;r<4;r++){ m_run[r] = -1e30f; l_run[r] = 0.f; }
  const float scl = 0.08838834764831845f;

  for (int kc=0; kc<=rt1; kc++){
    __syncthreads();
    // K tile: 8 waves x 8 rows (2 g2l16 each)
    #pragma unroll
    for (int j=0;j<2;j++){
      const int row = (w<<3) + (j<<2) + (lane>>4);
      const u16* src = kb + base + (size_t)(kc*64 + row)*1024
                       + ((size_t)((lane&15) ^ (row&7)) << 3);
      g2l16(src, Ks + (((w<<3)+(j<<2))<<7));
    }
    // V tile transposed: 8 waves x 16 dv-cols
    {
      const int kr = lane, d0 = w<<4;
      const u16* vsrc = vb + base + (size_t)(kc*64+kr)*1024 + d0;
      #pragma unroll
      for (int jj=0;jj<2;jj++){
        const uint4 vv = *(const uint4*)(vsrc + jj*8);
        u16 tmp[8]; *(uint4*)tmp = vv;
        #pragma unroll
        for (int e=0;e<8;e++){
          const int dv = d0 + jj*8 + e;
          Vt[(dv<<6) + (kr ^ ((dv&7)<<3))] = tmp[e];
        }
      }
    }
    __syncthreads();
    if (kc <= myrt){
      f32x4 sv[4];
      #pragma unroll
      for (int j=0;j<4;j++) sv[j] = (f32x4){0.f,0.f,0.f,0.f};
      #pragma unroll
      for (int ks=0;ks<4;ks++)
        #pragma unroll
        for (int j=0;j<4;j++){
          const bf16x8 bk = *(const bf16x8*)&Ks[(((j<<4)+c)<<7) + ((((ks<<2)|g) ^ (c&7))<<3)];
          sv[j] = __builtin_amdgcn_mfma_f32_16x16x32_bf16(af[ks], bk, sv[j], 0,0,0);
        }
      const bool diag = (kc==myrt);
      float p[4][4], rm[4], rsum[4];
      #pragma unroll
      for (int r=0;r<4;r++){
        float mx = -1e30f;
        #pragma unroll
        for (int j=0;j<4;j++){
          float svv = sv[j][r]*scl;
          if (diag && ((j<<4)+c) > ((wl<<4) + (g<<2) + r)) svv = -1e30f;
          p[j][r] = svv;
          mx = fmaxf(mx, svv);
        }
        rm[r] = mx;
      }
      #pragma unroll
      for (int o=1;o<16;o<<=1)
        #pragma unroll
        for (int r=0;r<4;r++) rm[r] = fmaxf(rm[r], __shfl_xor(rm[r], o));
      #pragma unroll
      for (int r=0;r<4;r++){
        const float mn = fmaxf(m_run[r], rm[r]);
        const float sc = __expf(m_run[r] - mn);
        m_run[r] = mn;
        float sum = 0.f;
        #pragma unroll
        for (int j=0;j<4;j++){ p[j][r] = __expf(p[j][r]-mn); sum += p[j][r]; }
        rsum[r] = sum;
        l_run[r] *= sc;
        #pragma unroll
        for (int f=0;f<8;f++) acc[f][r] *= sc;
      }
      #pragma unroll
      for (int o=1;o<16;o<<=1)
        #pragma unroll
        for (int r=0;r<4;r++) rsum[r] += __shfl_xor(rsum[r], o);
      #pragma unroll
      for (int r=0;r<4;r++) l_run[r] += rsum[r];
      // P -> LDS (wave-local rows within this wave's 16-row block)
      u16* Pw = Ps + (w<<10);              // 16 rows x 64 cols per wave
      #pragma unroll
      for (int j=0;j<4;j++)
        #pragma unroll
        for (int r=0;r<4;r++){
          const int prow = (g<<2)+r;
          Pw[(prow<<6) + (((j<<4)+c) ^ ((prow&7)<<3))] = f2b(p[j][r]);
        }
      #pragma unroll
      for (int ks2=0; ks2<2; ks2++){
        const bf16x8 pa = *(const bf16x8*)&Pw[(c<<6) + ((((ks2<<2)|g) ^ (c&7))<<3)];
        #pragma unroll
        for (int f=0;f<8;f++){
          const int dv = (f<<4)+c;
          const bf16x8 bv = *(const bf16x8*)&Vt[(dv<<6) + ((((ks2<<2)|g) ^ (c&7))<<3)];
          acc[f] = __builtin_amdgcn_mfma_f32_16x16x32_bf16(pa, bv, acc[f], 0,0,0);
        }
      }
    }
  }
  // ---- epilogue: memT+z stage (8 waves x 16 rows) ----
  __syncthreads();
  {
    const size_t mbase = (((size_t)b*8+h)*8+seg) << 14;
    #pragma unroll
    for (int i=0;i<4;i++){
      const int row = (w<<4) + (i<<2) + (lane>>4);
      const u16* src = memBT + mbase + ((size_t)row<<7)
                       + ((size_t)((lane&15) ^ (row&7)) << 3);
      g2l16(src, smem + (((w<<4)+(i<<2))<<7));
    }
    if (t < 128) zP[t] = zB[((((size_t)b*8+h)*8+seg)<<7) + t];
  }
  __syncthreads();
  // elu(Q)+1 in place (af -> sq fragments) + fp32 z-dot partial
  float dpart = 0.f;
  #pragma unroll
  for (int ks=0;ks<4;ks++){
    float f[8]; unpack8(__builtin_bit_cast(uint4, af[ks]), f);
    #pragma unroll
    for (int e=0;e<8;e++){
      f[e] = f[e]>0.f ? f[e]+1.f : __expf(f[e]);
      dpart += f[e] * zP[ks*32 + (g<<3) + e];
    }
    af[ks] = __builtin_bit_cast(bf16x8, pack8(f));
  }
  dpart += __shfl_xor(dpart, 16);
  dpart += __shfl_xor(dpart, 32);        // = den of q-row (wl*16+c), all g
  float den[4];
  #pragma unroll
  for (int r=0;r<4;r++) den[r] = 1.f / __shfl(dpart, (g<<2)+r);
  // retrieval folded per-f + gated combine + direct stores
  #pragma unroll 2
  for (int f=0;f<8;f++){
    f32x4 nf = {0.f,0.f,0.f,0.f};
    #pragma unroll
    for (int ks=0;ks<4;ks++){
      const bf16x8 bm = *(const bf16x8*)&smem[(((f<<4)+c)<<7) + ((((ks<<2)|g) ^ (c&7))<<3)];
      nf = __builtin_amdgcn_mfma_f32_16x16x32_bf16(af[ks], bm, nf, 0,0,0);
    }
    const float bv = betas[(h<<7) + (f<<4) + c];
    const float gate = 1.f/(1.f+__expf(-bv));
    #pragma unroll
    for (int r=0;r<4;r++){
      const size_t idx = base + (size_t)(myrt*64 + (wl<<4) + (g<<2) + r)*1024 + (f<<4) + c;
      const float att = acc[f][r] / l_run[r];
      const float am  = nf[r] * den[r];
      attc[idx] = f2b(gate*am + (1.f-gate)*att);
    }
  }
}

extern "C" void kernel_launch(void* const* d_in, const int* in_sizes, int n_in,
                              void* d_out, int out_size, void* d_ws, size_t ws_size,
                              hipStream_t stream)
{
  (void)in_sizes; (void)n_in; (void)out_size; (void)ws_size;
  const float* x    = (const float*)d_in[0];
  const float* ln_g = (const float*)d_in[1];
  const float* ln_b = (const float*)d_in[2];
  const float* Wq   = (const float*)d_in[3];
  const float* Wk   = (const float*)d_in[4];
  const float* Wv   = (const float*)d_in[5];
  const float* Wo   = (const float*)d_in[6];
  const float* betas= (const float*)d_in[7];
  const float* w1   = (const float*)d_in[8];
  const float* b1   = (const float*)d_in[9];
  const float* w2   = (const float*)d_in[10];
  const float* b2   = (const float*)d_in[11];
  float* out = (float*)d_out;

  // ---- workspace: 96 MB qkv + 24 MB bf16 weights = 120 MB ----
  char* ws = (char*)d_ws;
  const size_t MB = 1048576;
  u16* qb  = (u16*)(ws);              // qb -> at (in-place) -> FF hidden (w/ kb)
  u16* kb  = (u16*)(ws + 32*MB);      // kb -> FF hidden (second half)
  u16* vb  = (u16*)(ws + 64*MB);      // vb -> h2 (LN2 out)
  u16* Wqkv= (u16*)(ws + 96*MB);      // [3072][1024] bf16 (Wq|Wk|Wv rows)
  u16* Wob = (u16*)(ws + 102*MB);
  u16* w1b = (u16*)(ws + 104*MB);     // [4096][1024], 8 MB
  u16* w2b = (u16*)(ws + 112*MB);     // [1024][4096], 8 MB
  // ---- d_out doubles as scratch before the Wo GEMM overwrites it ----
  char* ob = (char*)d_out;
  u16*   h    = (u16*)ob;             // 32 MB bf16 (LN1 out; dead after QKV)
  float* Mseg = (float*)(ob + 32*MB); // 16 MB
  u16*   memBT= (u16*)  (ob + 48*MB); // 8 MB
  float* zseg = (float*)(ob + 56*MB); // 128 KB
  float* zB   = (float*)(ob + 56*MB + 131072);
  u16*   at   = qb;
  u16*   h2   = vb;                   // LN2 out lives in vb (free after attn)
  u16*   gb2  = qb;                   // FF hidden chunk: 64 MB spanning qb+kb

  // weight conversion (fp32 [K][N] -> bf16 [N][K])
  wconv_k<<<dim3(32,32),256,0,stream>>>(Wq, Wqkv,              1024,1024);
  wconv_k<<<dim3(32,32),256,0,stream>>>(Wk, Wqkv+1024*1024,    1024,1024);
  wconv_k<<<dim3(32,32),256,0,stream>>>(Wv, Wqkv+2*1024*1024,  1024,1024);
  wconv_k<<<dim3(32,32),256,0,stream>>>(Wo, Wob, 1024,1024);
  wconv_k<<<dim3(128,32),256,0,stream>>>(w1, w1b, 1024,4096);
  wconv_k<<<dim3(32,128),256,0,stream>>>(w2, w2b, 4096,1024);

  ln_k<<<16384,256,0,stream>>>(x, ln_g, ln_b, h);
  // fused QKV: [16384,1024] x [1024,3072] -> qb|kb|vb
  gemm3_k<EPI_QKV><<<dim3(12,128),512,0,stream>>>(h, Wqkv, 1024,1024,1024, 3072,
                                                  qb, nullptr, nullptr, nullptr);
  memseg_k<<<256,256,0,stream>>>(kb, vb, Mseg, zseg);
  scan_k<<<256,256,0,stream>>>(Mseg, zseg, memBT, zB);
  attn_k<<<1024,512,0,stream>>>(qb, kb, vb, memBT, zB, betas, at);
  gemm3_k<EPI_WO><<<dim3(4,128),512,0,stream>>>(at, Wob, 1024,1024,1024, 1024,
                                                nullptr, out, x, nullptr);
  ln_k<<<16384,256,0,stream>>>(out, ln_g, ln_b, h2);
  // FF chunked over HIDDEN dim: 2 chunks of 2048 cols (hidden chunk = 64 MB in qb+kb)
  for (int cc = 0; cc < 2; cc++){
    gemm3_k<EPI_GELU><<<dim3(8,128),512,0,stream>>>(h2, w1b + (size_t)cc*2048*1024,
                                                    1024,1024,1024, 2048,
                                                    gb2, nullptr, nullptr, b1 + cc*2048);
    gemm3_k<EPI_FF2><<<dim3(4,128),512,0,stream>>>(gb2, w2b + (size_t)cc*2048,
                                                   2048,2048,4096, 1024,
                                                   nullptr, out, nullptr,
                                                   cc==0 ? b2 : nullptr);
  }
}

// Round 20
// 666.642 us; speedup vs baseline: 1.1766x; 1.0149x over previous
//
#include <hip/hip_runtime.h>

typedef unsigned short u16;
typedef unsigned int   u32;
typedef float f32x4 __attribute__((ext_vector_type(4)));
typedef short bf16x8 __attribute__((ext_vector_type(8)));

#define DEV static __device__ __forceinline__

DEV u16 f2b(float f){
  u32 u = __builtin_bit_cast(u32, f);
  return (u16)((u + 0x7fffu + ((u >> 16) & 1u)) >> 16);
}
DEV float b2f(u16 h){ u32 u = ((u32)h) << 16; return __builtin_bit_cast(float, u); }
DEV u32 pack2(float a, float b){ return (u32)f2b(a) | ((u32)f2b(b) << 16); }
DEV uint4 pack8(const float* f){
  uint4 r; r.x = pack2(f[0],f[1]); r.y = pack2(f[2],f[3]);
  r.z = pack2(f[4],f[5]); r.w = pack2(f[6],f[7]); return r;
}
DEV void unpack8(uint4 u, float* f){
  f[0]=b2f((u16)(u.x&0xffffu)); f[1]=b2f((u16)(u.x>>16));
  f[2]=b2f((u16)(u.y&0xffffu)); f[3]=b2f((u16)(u.y>>16));
  f[4]=b2f((u16)(u.z&0xffffu)); f[5]=b2f((u16)(u.z>>16));
  f[6]=b2f((u16)(u.w&0xffffu)); f[7]=b2f((u16)(u.w>>16));
}
// gelu-tanh via sigmoid identity: 0.5x(1+tanh(z)) = x*sigma(2z); hardware v_exp
DEV float gelu_t(float x){
  const float z2 = 1.5957691216057308f*(x + 0.044715f*x*x*x);
  return x / (1.f + __expf(-z2));
}
// async global->LDS, 16B per lane; LDS dest = wave-uniform base + lane*16
DEV void g2l16(const u16* g, u16* l){
  __builtin_amdgcn_global_load_lds(
    (const __attribute__((address_space(1))) u32*)g,
    (__attribute__((address_space(3))) u32*)l, 16, 0, 0);
}

// ---------------- LayerNorm: fp32 [rows][1024] -> bf16 ----------------
__global__ __launch_bounds__(256)
void ln_k(const float* __restrict__ x, const float* __restrict__ gamma,
          const float* __restrict__ beta, u16* __restrict__ out)
{
  const int row = blockIdx.x;
  const int t = threadIdx.x;
  const float4 v = ((const float4*)(x + (size_t)row*1024))[t];
  float s  = v.x+v.y+v.z+v.w;
  float ss = v.x*v.x+v.y*v.y+v.z*v.z+v.w*v.w;
  #pragma unroll
  for (int o=32;o;o>>=1){ s += __shfl_xor(s,o); ss += __shfl_xor(ss,o); }
  __shared__ float rs[4], rq[4];
  if ((t&63)==0){ rs[t>>6]=s; rq[t>>6]=ss; }
  __syncthreads();
  s  = rs[0]+rs[1]+rs[2]+rs[3];
  ss = rq[0]+rq[1]+rq[2]+rq[3];
  const float mean = s*(1.f/1024.f);
  const float var  = ss*(1.f/1024.f) - mean*mean;
  const float inv  = rsqrtf(var + 1e-5f);
  const float4 g4 = ((const float4*)gamma)[t];
  const float4 b4 = ((const float4*)beta)[t];
  float o[4];
  o[0]=(v.x-mean)*inv*g4.x+b4.x; o[1]=(v.y-mean)*inv*g4.y+b4.y;
  o[2]=(v.z-mean)*inv*g4.z+b4.z; o[3]=(v.w-mean)*inv*g4.w+b4.w;
  uint2 w; w.x = pack2(o[0],o[1]); w.y = pack2(o[2],o[3]);
  *(uint2*)(out + (size_t)row*1024 + t*4) = w;
}

// --- merged weight conversion: all 6 matrices, fp32 [K][N] -> bf16 [N][K] ---
// blocks 0..4095: Wq/Wk/Wv/Wo (1024 ea); 4096..8191: w1; 8192..12287: w2.
__global__ __launch_bounds__(256)
void wconv6_k(const float* __restrict__ Wq, const float* __restrict__ Wk,
              const float* __restrict__ Wv, const float* __restrict__ Wo,
              const float* __restrict__ w1, const float* __restrict__ w2,
              u16* __restrict__ Wqkv, u16* __restrict__ Wob,
              u16* __restrict__ w1b, u16* __restrict__ w2b)
{
  const int bid = blockIdx.x;
  const float* W; u16* WT; int K, N, bx, by;
  if (bid < 4096){
    const int m = bid >> 10, idx = bid & 1023;
    K = 1024; N = 1024; bx = idx & 31; by = idx >> 5;
    W  = (m==0)?Wq:(m==1)?Wk:(m==2)?Wv:Wo;
    WT = (m<3) ? (Wqkv + (size_t)m*1024*1024) : Wob;
  } else if (bid < 8192){
    const int idx = bid - 4096;
    K = 1024; N = 4096; bx = idx & 127; by = idx >> 7;
    W = w1; WT = w1b;
  } else {
    const int idx = bid - 8192;
    K = 4096; N = 1024; bx = idx & 31; by = idx >> 5;
    W = w2; WT = w2b;
  }
  __shared__ float tile[32][33];
  const int k0 = by<<5, n0 = bx<<5;
  const int tx = threadIdx.x & 31, ty = threadIdx.x >> 5;   // 32 x 8
  #pragma unroll
  for (int r=0;r<32;r+=8)
    tile[ty+r][tx] = W[(size_t)(k0+ty+r)*N + n0+tx];
  __syncthreads();
  #pragma unroll
  for (int r=0;r<32;r+=8)
    WT[(size_t)(n0+ty+r)*K + k0+tx] = f2b(tile[tx][ty+r]);
}

// ---- bf16 MFMA GEMM, 128x256 tile, BK=32, dbuf + early-issue + XOR swizzle ----
#define EPI_QKV  0
#define EPI_WO   1
#define EPI_GELU 2
#define EPI_FF2  3   // out = out + acc + bias(chunk0 only) : RMW accumulate

template<int EPI>
__global__ __launch_bounds__(512)
void gemm3_k(const u16* __restrict__ A, const u16* __restrict__ BT,
             int K, int lda, int ldb, int N,
             u16* __restrict__ obf, float* __restrict__ of32,
             const float* __restrict__ res, const float* __restrict__ bias)
{
  __shared__ __align__(16) u16 SA[2*4096];    // [buf][128 rows][32 k]
  __shared__ __align__(16) u16 SB[2*8192];    // [buf][256 rows][32 k]
  const int t = threadIdx.x, wid = t>>6, lane = t&63;
  const int c = lane&15, g = lane>>4;
  const int wm = wid>>2, wn = wid&3;
  const int nwg = gridDim.x*gridDim.y;
  const int lb = blockIdx.y*gridDim.x + blockIdx.x;
  const int nl = (lb&7)*(nwg>>3) + (lb>>3);
  const int bx = nl % gridDim.x, by = nl / gridDim.x;
  const int m0 = by<<7, n0 = bx<<8;
  const int srow = lane>>2;
  const int scol = (lane&3)<<3;
  const int sxor = (srow&3)<<3;
  const int rowA = (wid<<4) + srow;
  const u16* aSrc  = A  + (size_t)(m0 + rowA)*lda + (scol ^ sxor);
  const u16* bSrc0 = BT + (size_t)(n0 + rowA)*ldb + (scol ^ sxor);
  const u16* bSrc1 = BT + (size_t)(n0 + 128 + rowA)*ldb + (scol ^ sxor);
  const int kx = (g<<3) ^ ((c&3)<<3);

  f32x4 acc[4][4];
  const f32x4 zz = {0.f,0.f,0.f,0.f};
  #pragma unroll
  for (int i=0;i<4;i++){ acc[i][0]=zz; acc[i][1]=zz; acc[i][2]=zz; acc[i][3]=zz; }

  g2l16(aSrc,  &SA[wid<<9]);
  g2l16(bSrc0, &SB[wid<<9]);
  g2l16(bSrc1, &SB[(wid<<9) + 4096]);
  __syncthreads();

  const int nt = K >> 5;
  for (int tt = 0; tt < nt; ++tt){
    const int cur = tt & 1;
    if (tt + 1 < nt){
      const int ko = (tt+1) << 5;
      g2l16(aSrc + ko,  &SA[((cur^1)<<12) + (wid<<9)]);
      g2l16(bSrc0 + ko, &SB[((cur^1)<<13) + (wid<<9)]);
      g2l16(bSrc1 + ko, &SB[((cur^1)<<13) + (wid<<9) + 4096]);
    }
    bf16x8 af[4], bf[4];
    #pragma unroll
    for (int i=0;i<4;i++)
      af[i] = *(const bf16x8*)&SA[(cur<<12) + ((wm<<6)+(i<<4)+c)*32 + kx];
    #pragma unroll
    for (int j=0;j<4;j++)
      bf[j] = *(const bf16x8*)&SB[(cur<<13) + ((wn<<6)+(j<<4)+c)*32 + kx];
    #pragma unroll
    for (int i=0;i<4;i++)
      #pragma unroll
      for (int j=0;j<4;j++)
        acc[i][j] = __builtin_amdgcn_mfma_f32_16x16x32_bf16(af[i], bf[j], acc[i][j], 0,0,0);
    __syncthreads();
  }

  #pragma unroll
  for (int i=0;i<4;i++){
    const int gr0 = m0 + (wm<<6) + (i<<4) + (g<<2);
    #pragma unroll
    for (int j=0;j<4;j++){
      const int gc = n0 + (wn<<6) + (j<<4) + c;
      #pragma unroll
      for (int r=0;r<4;r++){
        const int gr = gr0 + r;
        const float vv = acc[i][j][r];
        if (EPI==EPI_QKV){
          obf[((size_t)(gc>>10)<<24) + (size_t)gr*1024 + (gc&1023)] = f2b(vv);
        } else if (EPI==EPI_WO){
          const size_t idx = (size_t)gr*N + gc;
          of32[idx] = res[idx] + vv;
        } else if (EPI==EPI_GELU){
          obf[(size_t)gr*N + gc] = f2b(gelu_t(vv + bias[gc]));
        } else {
          const size_t idx = (size_t)gr*N + gc;
          of32[idx] = of32[idx] + vv + (bias ? bias[gc] : 0.f);
        }
      }
    }
  }
}

// ------- per-segment memory contribution (MFMA): Mseg = elu(K)^T V, zseg -------
__global__ __launch_bounds__(256)
void memseg_k(const u16* __restrict__ kb, const u16* __restrict__ vb,
              float* __restrict__ Mseg, float* __restrict__ zseg)
{
  const int bid = blockIdx.x;           // b*64 + h*8 + seg
  const int seg = bid & 7, h = (bid>>3)&7, b = bid>>6;
  __shared__ __align__(16) u16 Kt[128*64];   // [dk][s] swizzled
  __shared__ __align__(16) u16 Vt[128*64];   // [dv][s] swizzled
  const int t=threadIdx.x, w=t>>6, lane=t&63, c=lane&15, g=lane>>4;

  f32x4 acc[2][8];
  f32x4 zacc[2];
  const f32x4 zzero = {0.f,0.f,0.f,0.f};
  #pragma unroll
  for (int d=0;d<2;d++){ zacc[d]=zzero;
    #pragma unroll
    for (int j=0;j<8;j++) acc[d][j]=zzero; }
  bf16x8 bones;
  { u16 tmp[8];
    #pragma unroll
    for (int e=0;e<8;e++) tmp[e] = (c==0) ? (u16)0x3F80 : (u16)0;
    bones = __builtin_bit_cast(bf16x8, *(uint4*)tmp); }

  for (int s0=0; s0<512; s0+=64){
    __syncthreads();
    {
      const int s = lane, dk0 = w<<5;
      const size_t grow = ((size_t)b*4096 + seg*512 + s0 + s)*1024 + h*128 + dk0;
      #pragma unroll
      for (int jj=0;jj<4;jj++){
        float kf[8], vf[8];
        unpack8(*(const uint4*)(kb + grow + jj*8), kf);
        unpack8(*(const uint4*)(vb + grow + jj*8), vf);
        #pragma unroll
        for (int e=0;e<8;e++){
          const int dk = dk0 + jj*8 + e;
          const float ek = kf[e]>0.f ? kf[e]+1.f : __expf(kf[e]);   // elu+1
          Kt[(dk<<6) + (s ^ ((dk&7)<<3))] = f2b(ek);
          Vt[(dk<<6) + (s ^ ((dk&7)<<3))] = f2b(vf[e]);
        }
      }
    }
    __syncthreads();
    #pragma unroll
    for (int ks=0;ks<2;ks++){
      const int kc = (ks<<5) + (g<<3);
      const bf16x8 a0 = *(const bf16x8*)&Kt[((((w<<1)  )*16 + c)<<6) + (kc ^ ((c&7)<<3))];
      const bf16x8 a1 = *(const bf16x8*)&Kt[((((w<<1)+1)*16 + c)<<6) + (kc ^ ((c&7)<<3))];
      zacc[0] = __builtin_amdgcn_mfma_f32_16x16x32_bf16(a0, bones, zacc[0], 0,0,0);
      zacc[1] = __builtin_amdgcn_mfma_f32_16x16x32_bf16(a1, bones, zacc[1], 0,0,0);
      #pragma unroll
      for (int j=0;j<8;j++){
        const bf16x8 bv = *(const bf16x8*)&Vt[(((j<<4) + c)<<6) + (kc ^ ((c&7)<<3))];
        acc[0][j] = __builtin_amdgcn_mfma_f32_16x16x32_bf16(a0, bv, acc[0][j], 0,0,0);
        acc[1][j] = __builtin_amdgcn_mfma_f32_16x16x32_bf16(a1, bv, acc[1][j], 0,0,0);
      }
    }
  }
  const size_t mb = (size_t)bid*16384;
  #pragma unroll
  for (int d=0;d<2;d++){
    const int dk = ((w<<1)+d)*16 + (g<<2);
    #pragma unroll
    for (int j=0;j<8;j++)
      #pragma unroll
      for (int r=0;r<4;r++)
        Mseg[mb + (size_t)(dk + r)*128 + (j<<4) + c] = acc[d][j][r];
    if (c==0){
      #pragma unroll
      for (int r=0;r<4;r++) zseg[(size_t)bid*128 + dk + r] = zacc[d][r];
    }
  }
}

// --- prefix scan over segments -> memBT (TRANSPOSED [dv][kd], bf16), zB ---
__global__ __launch_bounds__(256)
void scan_k(const float* __restrict__ Mseg, const float* __restrict__ zseg,
            u16* __restrict__ memBT, float* __restrict__ zB)
{
  const int bh = blockIdx.x >> 3, oct = blockIdx.x & 7;
  const int t = threadIdx.x;
  const int dv = (oct<<4) + (t&15);
  const int kd0 = (t>>4)<<3;
  float run[8];
  #pragma unroll
  for (int i=0;i<8;i++) run[i]=0.f;
  for (int seg=0; seg<8; seg++){
    const size_t base = ((size_t)bh*8 + seg)*16384;
    u16 tmp[8];
    #pragma unroll
    for (int i=0;i<8;i++) tmp[i] = f2b(run[i]);
    *(uint4*)(memBT + base + (size_t)dv*128 + kd0) = *(const uint4*)tmp;
    #pragma unroll
    for (int i=0;i<8;i++) run[i] += Mseg[base + (size_t)(kd0+i)*128 + dv];
  }
  if (oct==0 && t < 128){
    float zr = 1.f/128.f;
    for (int seg=0; seg<8; seg++){
      const size_t base = ((size_t)bh*8 + seg)*128;
      zB[base + t] = zr;
      zr += zseg[base + t];
    }
  }
}

// --- flash local attention + fused retrieval, rt-PAIRED: 1024 blocks x 512 thr ---
__global__ __launch_bounds__(512,2)
void attn_k(const u16* __restrict__ qb, const u16* __restrict__ kb,
            const u16* __restrict__ vb, const u16* __restrict__ memBT,
            const float* __restrict__ zB, const float* __restrict__ betas,
            u16* __restrict__ attc)
{
  const int bid = blockIdx.x;
  const int s = bid & 255;                 // (b,h,seg)
  const int pr = 3 - (bid >> 8);           // pair index, heavy first
  const int seg = s&7, h=(s>>3)&7, b=s>>6;
  __shared__ __align__(16) u16 smem[16384];  // Ks[0,8192)+Vt[8192,16384); epi: memT
  __shared__ __align__(16) u16 Ps[8192];     // P 128x64 (two 64-row halves); epi: z
  u16* Ks = smem;
  u16* Vt = smem + 8192;
  float* zP = (float*)Ps;
  const int t=threadIdx.x, w=t>>6, lane=t&63, c=lane&15, g=lane>>4;
  const int half = w>>2, wl = w&3;         // half: 0->rt0, 1->rt1
  const int myrt = (pr<<1) + half;
  const int rt1  = (pr<<1) + 1;
  const size_t base = ((size_t)b*4096 + seg*512)*1024 + h*128;

  bf16x8 af[4];
  {
    const u16* qsrc = qb + base + (size_t)(myrt*64 + (wl<<4) + c)*1024 + (g<<3);
    #pragma unroll
    for (int ks=0;ks<4;ks++) af[ks] = *(const bf16x8*)(qsrc + ks*32);
  }
  f32x4 acc[8];
  #pragma unroll
  for (int f=0;f<8;f++) acc[f] = (f32x4){0.f,0.f,0.f,0.f};
  float m_run[4], l_run[4];
  #pragma unroll
  for (int r=0;r<4;r++){ m_run[r] = -1e30f; l_run[r] = 0.f; }
  const float scl = 0.08838834764831845f;

  for (int kc=0; kc<=rt1; kc++){
    __syncthreads();
    #pragma unroll
    for (int j=0;j<2;j++){
      const int row = (w<<3) + (j<<2) + (lane>>4);
      const u16* src = kb + base + (size_t)(kc*64 + row)*1024
                       + ((size_t)((lane&15) ^ (row&7)) << 3);
      g2l16(src, Ks + (((w<<3)+(j<<2))<<7));
    }
    {
      const int kr = lane, d0 = w<<4;
      const u16* vsrc = vb + base + (size_t)(kc*64+kr)*1024 + d0;
      #pragma unroll
      for (int jj=0;jj<2;jj++){
        const uint4 vv = *(const uint4*)(vsrc + jj*8);
        u16 tmp[8]; *(uint4*)tmp = vv;
        #pragma unroll
        for (int e=0;e<8;e++){
          const int dv = d0 + jj*8 + e;
          Vt[(dv<<6) + (kr ^ ((dv&7)<<3))] = tmp[e];
        }
      }
    }
    __syncthreads();
    if (kc <= myrt){
      f32x4 sv[4];
      #pragma unroll
      for (int j=0;j<4;j++) sv[j] = (f32x4){0.f,0.f,0.f,0.f};
      #pragma unroll
      for (int ks=0;ks<4;ks++)
        #pragma unroll
        for (int j=0;j<4;j++){
          const bf16x8 bk = *(const bf16x8*)&Ks[(((j<<4)+c)<<7) + ((((ks<<2)|g) ^ (c&7))<<3)];
          sv[j] = __builtin_amdgcn_mfma_f32_16x16x32_bf16(af[ks], bk, sv[j], 0,0,0);
        }
      const bool diag = (kc==myrt);
      float p[4][4], rm[4], rsum[4];
      #pragma unroll
      for (int r=0;r<4;r++){
        float mx = -1e30f;
        #pragma unroll
        for (int j=0;j<4;j++){
          float svv = sv[j][r]*scl;
          if (diag && ((j<<4)+c) > ((wl<<4) + (g<<2) + r)) svv = -1e30f;
          p[j][r] = svv;
          mx = fmaxf(mx, svv);
        }
        rm[r] = mx;
      }
      #pragma unroll
      for (int o=1;o<16;o<<=1)
        #pragma unroll
        for (int r=0;r<4;r++) rm[r] = fmaxf(rm[r], __shfl_xor(rm[r], o));
      #pragma unroll
      for (int r=0;r<4;r++){
        const float mn = fmaxf(m_run[r], rm[r]);
        const float sc = __expf(m_run[r] - mn);
        m_run[r] = mn;
        float sum = 0.f;
        #pragma unroll
        for (int j=0;j<4;j++){ p[j][r] = __expf(p[j][r]-mn); sum += p[j][r]; }
        rsum[r] = sum;
        l_run[r] *= sc;
        #pragma unroll
        for (int f=0;f<8;f++) acc[f][r] *= sc;
      }
      #pragma unroll
      for (int o=1;o<16;o<<=1)
        #pragma unroll
        for (int r=0;r<4;r++) rsum[r] += __shfl_xor(rsum[r], o);
      #pragma unroll
      for (int r=0;r<4;r++) l_run[r] += rsum[r];
      u16* Pw = Ps + (w<<10);              // 16 rows x 64 cols per wave
      #pragma unroll
      for (int j=0;j<4;j++)
        #pragma unroll
        for (int r=0;r<4;r++){
          const int prow = (g<<2)+r;
          Pw[(prow<<6) + (((j<<4)+c) ^ ((prow&7)<<3))] = f2b(p[j][r]);
        }
      #pragma unroll
      for (int ks2=0; ks2<2; ks2++){
        const bf16x8 pa = *(const bf16x8*)&Pw[(c<<6) + ((((ks2<<2)|g) ^ (c&7))<<3)];
        #pragma unroll
        for (int f=0;f<8;f++){
          const int dv = (f<<4)+c;
          const bf16x8 bv = *(const bf16x8*)&Vt[(dv<<6) + ((((ks2<<2)|g) ^ (c&7))<<3)];
          acc[f] = __builtin_amdgcn_mfma_f32_16x16x32_bf16(pa, bv, acc[f], 0,0,0);
        }
      }
    }
  }
  // ---- epilogue: memT+z stage (8 waves x 16 rows) ----
  __syncthreads();
  {
    const size_t mbase = (((size_t)b*8+h)*8+seg) << 14;
    #pragma unroll
    for (int i=0;i<4;i++){
      const int row = (w<<4) + (i<<2) + (lane>>4);
      const u16* src = memBT + mbase + ((size_t)row<<7)
                       + ((size_t)((lane&15) ^ (row&7)) << 3);
      g2l16(src, smem + (((w<<4)+(i<<2))<<7));
    }
    if (t < 128) zP[t] = zB[((((size_t)b*8+h)*8+seg)<<7) + t];
  }
  __syncthreads();
  float dpart = 0.f;
  #pragma unroll
  for (int ks=0;ks<4;ks++){
    float f[8]; unpack8(__builtin_bit_cast(uint4, af[ks]), f);
    #pragma unroll
    for (int e=0;e<8;e++){
      f[e] = f[e]>0.f ? f[e]+1.f : __expf(f[e]);
      dpart += f[e] * zP[ks*32 + (g<<3) + e];
    }
    af[ks] = __builtin_bit_cast(bf16x8, pack8(f));
  }
  dpart += __shfl_xor(dpart, 16);
  dpart += __shfl_xor(dpart, 32);
  float den[4];
  #pragma unroll
  for (int r=0;r<4;r++) den[r] = 1.f / __shfl(dpart, (g<<2)+r);
  #pragma unroll 2
  for (int f=0;f<8;f++){
    f32x4 nf = {0.f,0.f,0.f,0.f};
    #pragma unroll
    for (int ks=0;ks<4;ks++){
      const bf16x8 bm = *(const bf16x8*)&smem[(((f<<4)+c)<<7) + ((((ks<<2)|g) ^ (c&7))<<3)];
      nf = __builtin_amdgcn_mfma_f32_16x16x32_bf16(af[ks], bm, nf, 0,0,0);
    }
    const float bv = betas[(h<<7) + (f<<4) + c];
    const float gate = 1.f/(1.f+__expf(-bv));
    #pragma unroll
    for (int r=0;r<4;r++){
      const size_t idx = base + (size_t)(myrt*64 + (wl<<4) + (g<<2) + r)*1024 + (f<<4) + c;
      const float att = acc[f][r] / l_run[r];
      const float am  = nf[r] * den[r];
      attc[idx] = f2b(gate*am + (1.f-gate)*att);
    }
  }
}

extern "C" void kernel_launch(void* const* d_in, const int* in_sizes, int n_in,
                              void* d_out, int out_size, void* d_ws, size_t ws_size,
                              hipStream_t stream)
{
  (void)in_sizes; (void)n_in; (void)out_size; (void)ws_size;
  const float* x    = (const float*)d_in[0];
  const float* ln_g = (const float*)d_in[1];
  const float* ln_b = (const float*)d_in[2];
  const float* Wq   = (const float*)d_in[3];
  const float* Wk   = (const float*)d_in[4];
  const float* Wv   = (const float*)d_in[5];
  const float* Wo   = (const float*)d_in[6];
  const float* betas= (const float*)d_in[7];
  const float* w1   = (const float*)d_in[8];
  const float* b1   = (const float*)d_in[9];
  const float* w2   = (const float*)d_in[10];
  const float* b2   = (const float*)d_in[11];
  float* out = (float*)d_out;

  // ---- workspace: 96 MB qkv + 24 MB bf16 weights = 120 MB ----
  char* ws = (char*)d_ws;
  const size_t MB = 1048576;
  u16* qb  = (u16*)(ws);              // qb -> at (in-place) -> FF hidden (w/ kb)
  u16* kb  = (u16*)(ws + 32*MB);      // kb -> FF hidden (second half)
  u16* vb  = (u16*)(ws + 64*MB);      // vb -> h2 (LN2 out)
  u16* Wqkv= (u16*)(ws + 96*MB);      // [3072][1024] bf16 (Wq|Wk|Wv rows)
  u16* Wob = (u16*)(ws + 102*MB);
  u16* w1b = (u16*)(ws + 104*MB);     // [4096][1024], 8 MB
  u16* w2b = (u16*)(ws + 112*MB);     // [1024][4096], 8 MB
  // ---- d_out doubles as scratch before the Wo GEMM overwrites it ----
  char* ob = (char*)d_out;
  u16*   h    = (u16*)ob;             // 32 MB bf16 (LN1 out; dead after QKV)
  float* Mseg = (float*)(ob + 32*MB); // 16 MB
  u16*   memBT= (u16*)  (ob + 48*MB); // 8 MB
  float* zseg = (float*)(ob + 56*MB); // 128 KB
  float* zB   = (float*)(ob + 56*MB + 131072);
  u16*   at   = qb;
  u16*   h2   = vb;                   // LN2 out lives in vb (free after attn)
  u16*   gb2  = qb;                   // FF hidden chunk: 64 MB spanning qb+kb

  // merged weight conversion (fp32 [K][N] -> bf16 [N][K]), one dispatch
  wconv6_k<<<12288,256,0,stream>>>(Wq, Wk, Wv, Wo, w1, w2, Wqkv, Wob, w1b, w2b);

  ln_k<<<16384,256,0,stream>>>(x, ln_g, ln_b, h);
  // fused QKV: [16384,1024] x [1024,3072] -> qb|kb|vb
  gemm3_k<EPI_QKV><<<dim3(12,128),512,0,stream>>>(h, Wqkv, 1024,1024,1024, 3072,
                                                  qb, nullptr, nullptr, nullptr);
  memseg_k<<<256,256,0,stream>>>(kb, vb, Mseg, zseg);
  scan_k<<<256,256,0,stream>>>(Mseg, zseg, memBT, zB);
  attn_k<<<1024,512,0,stream>>>(qb, kb, vb, memBT, zB, betas, at);
  gemm3_k<EPI_WO><<<dim3(4,128),512,0,stream>>>(at, Wob, 1024,1024,1024, 1024,
                                                nullptr, out, x, nullptr);
  ln_k<<<16384,256,0,stream>>>(out, ln_g, ln_b, h2);
  // FF chunked over HIDDEN dim: 2 chunks of 2048 cols (hidden chunk = 64 MB in qb+kb)
  for (int cc = 0; cc < 2; cc++){
    gemm3_k<EPI_GELU><<<dim3(8,128),512,0,stream>>>(h2, w1b + (size_t)cc*2048*1024,
                                                    1024,1024,1024, 2048,
                                                    gb2, nullptr, nullptr, b1 + cc*2048);
    gemm3_k<EPI_FF2><<<dim3(4,128),512,0,stream>>>(gb2, w2b + (size_t)cc*2048,
                                                   2048,2048,4096, 1024,
                                                   nullptr, out, nullptr,
                                                   cc==0 ? b2 : nullptr);
  }
}